// Round 2
// baseline (303.709 us; speedup 1.0000x reference)
//
#include <hip/hip_runtime.h>
#include <hip/hip_bf16.h>
#include <stdint.h>

typedef unsigned short u16;
typedef __attribute__((ext_vector_type(8))) __bf16 bf16x8;
typedef __attribute__((ext_vector_type(4))) float f32x4;

#define LOG2E 1.4426950408889634f

__device__ __forceinline__ float bf2f(u16 u) {
  union { uint32_t u; float f; } v; v.u = ((uint32_t)u) << 16;
  return v.f;
}

// packed cvt: two fp32 -> one u32 holding (lo=a, hi=b) bf16
__device__ __forceinline__ uint32_t pk2(float a, float b) {
  union { __hip_bfloat162 h; uint32_t u; } x;
  x.h = __float22bfloat162_rn(make_float2(a, b));
  return x.u;
}

__device__ __forceinline__ void gl_lds16(const void* g, void* l) {
  __builtin_amdgcn_global_load_lds((const __attribute__((address_space(1))) void*)g,
                                   (__attribute__((address_space(3))) void*)l,
                                   16, 0, 0);
}

__device__ __forceinline__ f32x4 mfma16(bf16x8 a, bf16x8 b, f32x4 c) {
  return __builtin_amdgcn_mfma_f32_16x16x32_bf16(a, b, c, 0, 0, 0);
}

// raw workgroup barrier with compiler memory fence (no vmcnt/lgkm drain)
__device__ __forceinline__ void bar() {
  asm volatile("" ::: "memory");
  __builtin_amdgcn_s_barrier();
  asm volatile("" ::: "memory");
}

// ---------------- fp32 -> bf16 elementwise (x) ----------------
__global__ void cvt_bf16(const float* __restrict__ src, u16* __restrict__ dst) {
  int i = (blockIdx.x * 256 + threadIdx.x) * 4;
  float4 f = *(const float4*)(src + i);
  uint2 o;
  o.x = pk2(f.x, f.y);
  o.y = pk2(f.z, f.w);
  *(uint2*)(dst + i) = o;
}

// ---------------- transpose + convert: W[k][n] fp32 -> Wt[n][k] bf16 ----------------
__global__ void transpose_cvt(const float* __restrict__ W0, const float* __restrict__ W1,
                              const float* __restrict__ W2, const float* __restrict__ W3,
                              u16* __restrict__ out) {
  __shared__ float tile[64][65];
  int z = blockIdx.z;
  const float* W = (z == 0) ? W0 : (z == 1) ? W1 : (z == 2) ? W2 : W3;
  u16* dst = out + (size_t)z * 2048 * 2048;
  int k0 = blockIdx.y * 64, n0 = blockIdx.x * 64;
  int lx = threadIdx.x & 63, ly = threadIdx.x >> 6;
#pragma unroll
  for (int p = 0; p < 16; ++p) {
    int row = p * 4 + ly;
    tile[row][lx] = W[(size_t)(k0 + row) * 2048 + n0 + lx];
  }
  __syncthreads();
  int kc = threadIdx.x & 7;        // 8-wide k chunk
  int rbase = threadIdx.x >> 3;    // 0..31
#pragma unroll
  for (int p = 0; p < 2; ++p) {
    int n = rbase + p * 32;        // n-local row
    uint4 o;
    o.x = pk2(tile[kc * 8 + 0][n], tile[kc * 8 + 1][n]);
    o.y = pk2(tile[kc * 8 + 2][n], tile[kc * 8 + 3][n]);
    o.z = pk2(tile[kc * 8 + 4][n], tile[kc * 8 + 5][n]);
    o.w = pk2(tile[kc * 8 + 6][n], tile[kc * 8 + 7][n]);
    *(uint4*)(dst + (size_t)(n0 + n) * 2048 + k0 + kc * 8) = o;
  }
}

// ---------------- QKV GEMM: 256x256 tile, 8 waves, 4-phase counted-vmcnt pipeline ----
// M=2048 (s), N=6144 (3 proj x 2048), K=2048. Grid 192 = 8 tm x 24 tn, XCD-swizzled.
// LDS 128 KB: buf b at b*64K; within: [A-kh0 | A-kh1 | B-kh0 | B-kh1] regions?
//   -> region order: u=0:A-kh0 @0, u=1:B-kh0 @16K, u=2:A-kh1 @32K, u=3:B-kh1 @48K.
// K-half layout: [256 rows][4 chunks of 16B], chunk = q ^ (row&3), row stride 64B.
//   bank = (row&1)*16 + (q^(row&3))*4 + w -> uniform 8/bank = b128 floor (conflict-free).
// Pipeline: during tile t's 4 phases we stage tile t+1's unit P into buf (t+1)&1 (not
// read until next tile -> safe after the phase barrier). Unit issued at phase p is
// first read at phase p+4; vmcnt(4) at each phase start (3 units = 6 loads in flight,
// wait until 4 remain -> oldest unit landed) + s_barrier makes ALL waves' copies of it
// visible. Last tile phases 2-3 drain (no issues left to count against).
__launch_bounds__(512, 2)
__global__ void gemm_qkv(const u16* __restrict__ A, const u16* __restrict__ Bt,
                         const float* __restrict__ b0, const float* __restrict__ b1,
                         const float* __restrict__ b2,
                         u16* __restrict__ outQ, u16* __restrict__ outK,
                         u16* __restrict__ outVT) {
  extern __shared__ char smem[];
  const int K = 2048, NT = 32;
  const int tid = threadIdx.x;
  const int lane = tid & 63, wid = tid >> 6;
  const int c = lane & 15, q = lane >> 4;
  const int wm = wid >> 2, wn = wid & 3;   // 2 x 4 waves; wave C = rows[wm*128,+128) x cols[wn*64,+64)
  // XCD-aware swizzle (192 % 8 == 0 -> simple form is bijective)
  int raw = blockIdx.x;
  int sbid = (raw & 7) * 24 + (raw >> 3);
  const int tm = sbid / 24, tn = sbid % 24;
  const size_t Abase = (size_t)tm * 256 * K;
  const size_t Bbase = (size_t)tn * 256 * K;

  f32x4 acc[8][4] = {};

  // stage unit u (0:A-kh0 1:B-kh0 2:A-kh1 3:B-kh1) of tile t2 into buf t2&1.
  // LDS dest linear (slot*16); source pre-permuted so that logical chunk-slot
  // j of row r holds global k-chunk q = j ^ (r&3)  (m173 source-permute).
  auto STAGE = [&](int t2, int u) {
    char* dst = smem + (t2 & 1) * 65536 + u * 16384;
    const u16* src = (u & 1) ? (Bt + Bbase) : (A + Abase);
    int kh = u >> 1;
#pragma unroll
    for (int l = 0; l < 2; ++l) {
      int s = l * 512 + wid * 64 + lane;     // slot 0..1023
      int r = s >> 2;                        // row 0..255
      int qq = (s & 3) ^ (r & 3);
      gl_lds16(src + (size_t)r * K + t2 * 64 + kh * 32 + qq * 8, dst + (size_t)s * 16);
    }
  };

#define QKV_PHASE(P)                                                              \
  {                                                                               \
    if (t == NT - 1 && (P) >= 2) { asm volatile("s_waitcnt vmcnt(0)" ::: "memory"); } \
    else                         { asm volatile("s_waitcnt vmcnt(4)" ::: "memory"); } \
    bar();                                                                        \
    if (t + 1 < NT) STAGE(t + 1, (P));                                            \
    const int kcP = (P) >> 1, nhP = (P) & 1;                                      \
    const char* Ab = smem + buf * 65536 + (kcP * 2) * 16384;                      \
    const char* Bb = smem + buf * 65536 + (kcP * 2 + 1) * 16384;                  \
    if (nhP == 0) {                                                               \
      _Pragma("unroll") for (int mi = 0; mi < 8; ++mi) {                          \
        int row = wm * 128 + mi * 16 + c;                                         \
        af[mi] = *(const bf16x8*)(Ab + row * 64 + ((q ^ (row & 3)) << 4));        \
      }                                                                           \
    }                                                                             \
    bf16x8 bfv[2];                                                                \
    _Pragma("unroll") for (int jj = 0; jj < 2; ++jj) {                            \
      int row = wn * 64 + (nhP * 2 + jj) * 16 + c;                                \
      bfv[jj] = *(const bf16x8*)(Bb + row * 64 + ((q ^ (row & 3)) << 4));         \
    }                                                                             \
    __builtin_amdgcn_s_setprio(1);                                                \
    _Pragma("unroll") for (int mi = 0; mi < 8; ++mi) {                            \
      acc[mi][nhP * 2 + 0] = mfma16(af[mi], bfv[0], acc[mi][nhP * 2 + 0]);        \
      acc[mi][nhP * 2 + 1] = mfma16(af[mi], bfv[1], acc[mi][nhP * 2 + 1]);        \
    }                                                                             \
    __builtin_amdgcn_s_setprio(0);                                                \
  }

  // prologue: stage tile 0 fully (8 loads/thread)
#pragma unroll
  for (int u = 0; u < 4; ++u) STAGE(0, u);

#pragma unroll 2
  for (int t = 0; t < NT; ++t) {
    const int buf = t & 1;
    bf16x8 af[8];
    QKV_PHASE(0)
    QKV_PHASE(1)
    QKV_PHASE(2)
    QKV_PHASE(3)
  }
#undef QKV_PHASE

  // ---- epilogue ----
  const int proj = tn >> 3;
  const int tnp = tn & 7;          // tile index within projection; heads tnp*2, tnp*2+1
  if (proj < 2) {
    u16* out = (proj == 0) ? outQ : outK;
    const float* bias = (proj == 0) ? b0 : b1;
    const float scale = (proj == 0) ? 0.08838834764831845f : 1.0f;
#pragma unroll
    for (int mi = 0; mi < 8; ++mi) {
      int s0 = tm * 256 + wm * 128 + mi * 16 + q * 4;
#pragma unroll
      for (int ni = 0; ni < 4; ++ni) {
        int colp = tnp * 256 + wn * 64 + ni * 16 + c;   // col within projection 0..2047
        int h = colp >> 7, d = colp & 127;
        float bv = bias[colp];
        uint32_t p01 = pk2((acc[mi][ni][0] + bv) * scale, (acc[mi][ni][1] + bv) * scale);
        uint32_t p23 = pk2((acc[mi][ni][2] + bv) * scale, (acc[mi][ni][3] + bv) * scale);
        u16* o = out + ((size_t)h * 2048 + s0) * 128 + d;
        o[0]   = (u16)p01;
        o[128] = (u16)(p01 >> 16);
        o[256] = (u16)p23;
        o[384] = (u16)(p23 >> 16);
      }
    }
  } else {
    // V: transpose via LDS -> Vt[h][d][s]; two passes (one per head-half of the tile)
    u16* Cs = (u16*)smem;   // [128 d][264 s-padded] u16 = 67.5 KB
#pragma unroll
    for (int hh = 0; hh < 2; ++hh) {
      bar();   // prior phase reads (hh=0) / pass reads (hh=1) complete
      if ((wn >> 1) == hh) {
#pragma unroll
        for (int mi = 0; mi < 8; ++mi) {
          int sl = wm * 128 + mi * 16 + q * 4;
#pragma unroll
          for (int ni = 0; ni < 4; ++ni) {
            int dl = (wn & 1) * 64 + ni * 16 + c;
            float bv = b2[tnp * 256 + hh * 128 + dl];
            uint2 pk;
            pk.x = pk2(acc[mi][ni][0] + bv, acc[mi][ni][1] + bv);
            pk.y = pk2(acc[mi][ni][2] + bv, acc[mi][ni][3] + bv);
            *(uint2*)(Cs + dl * 264 + sl) = pk;
          }
        }
      }
      bar();
#pragma unroll
      for (int kk = 0; kk < 8; ++kk) {
        int cid = kk * 512 + tid;
        int d = cid >> 5, sc = (cid & 31) * 8;
        uint4 vv = *(const uint4*)(Cs + d * 264 + sc);
        *(uint4*)(outVT + ((size_t)((tnp * 2 + hh) * 128 + d)) * 2048 + tm * 256 + sc) = vv;
      }
    }
  }
}

// ---------------- O-projection GEMM: 128x64 tiles for co-residency ----------------
__launch_bounds__(256, 2)
__global__ void gemm_op(const u16* __restrict__ A, const u16* __restrict__ Bt,
                        const float* __restrict__ bias, float* __restrict__ out) {
  extern __shared__ char smem[];
  u16* As = (u16*)smem;              // [128][64]  16 KB
  u16* Bs = (u16*)(smem + 16384);    // [64][64]    8 KB
  const int K = 2048;
  const int tid = threadIdx.x;
  const int lane = tid & 63, wid = tid >> 6;
  const int c = lane & 15, q = lane >> 4;
  const int wm = wid >> 1, wn = wid & 1;
  const int tm = blockIdx.y, tn = blockIdx.x;
  const size_t Abase = (size_t)tm * 128 * K;
  const size_t Bbase = (size_t)tn * 64 * K;

  f32x4 acc[4][2] = {};

  for (int kt = 0; kt < K / 64; ++kt) {
#pragma unroll
    for (int t = 0; t < 4; ++t) {
      int slot = wid * 256 + t * 64 + lane;
      int row = slot >> 3, cs = slot & 7;
      int cc = cs ^ (row & 7);
      gl_lds16(A + Abase + (size_t)row * K + kt * 64 + cc * 8,
               (char*)As + (size_t)(wid * 256 + t * 64) * 16);
    }
#pragma unroll
    for (int t = 0; t < 2; ++t) {
      int slot = wid * 128 + t * 64 + lane;
      int row = slot >> 3, cs = slot & 7;
      int cc = cs ^ (row & 7);
      gl_lds16(Bt + Bbase + (size_t)row * K + kt * 64 + cc * 8,
               (char*)Bs + (size_t)(wid * 128 + t * 64) * 16);
    }
    __syncthreads();
#pragma unroll
    for (int kc = 0; kc < 2; ++kc) {
      bf16x8 af[4], bfr[2];
#pragma unroll
      for (int i = 0; i < 4; ++i) {
        int rowa = wm * 64 + i * 16 + c;
        int cha = ((kc << 2) | q) ^ (rowa & 7);
        af[i] = *(const bf16x8*)((const char*)As + rowa * 128 + cha * 16);
      }
#pragma unroll
      for (int j = 0; j < 2; ++j) {
        int rowb = wn * 32 + j * 16 + c;
        int chb = ((kc << 2) | q) ^ (rowb & 7);
        bfr[j] = *(const bf16x8*)((const char*)Bs + rowb * 128 + chb * 16);
      }
#pragma unroll
      for (int i = 0; i < 4; ++i)
#pragma unroll
        for (int j = 0; j < 2; ++j)
          acc[i][j] = mfma16(af[i], bfr[j], acc[i][j]);
    }
    __syncthreads();
  }

#pragma unroll
  for (int i = 0; i < 4; ++i) {
    int rowg = tm * 128 + wm * 64 + i * 16 + q * 4;
#pragma unroll
    for (int j = 0; j < 2; ++j) {
      int colg = tn * 64 + wn * 32 + j * 16 + c;
      float bv = bias[colg];
#pragma unroll
      for (int r = 0; r < 4; ++r)
        out[(size_t)(rowg + r) * 2048 + colg] = acc[i][j][r] + bv;
    }
  }
}

// ---------------- flash attention, causal, split-K(2), max-free softmax ----------------
// Double-buffered K/V staging with counted vmcnt(8); P slab reuses the dead current
// K buffer after the QK^T barrier. Raw s_barrier (no vmcnt drain). 2 blocks/CU.
// Stores RAW partial O (bf16) + row-sum l (fp32 in d_out scratch); combine divides
// by (l0+l1). qt=0/split1 has l=0,O=0 rows — benign raw; NEVER normalize per-split.
__launch_bounds__(256, 2)
__global__ void attn_kernel(const u16* __restrict__ Qb, const u16* __restrict__ Kb,
                            const u16* __restrict__ Vt,
                            u16* __restrict__ Opb, float* __restrict__ lpb) {
  extern __shared__ char smem[];
  int b = blockIdx.x;
  int split, qt, h;
  if (b < 256) { split = 0; qt = b >> 4; h = b & 15; }
  else { split = 1; int idx = b - 256; qt = 15 - (idx >> 4); h = idx & 15; }
  u16* Op = Opb + (size_t)split * 4194304;
  float* lp = lpb + (size_t)split * 32768;
  const int ktBase = split ? (qt + 1) : 0;
  const int ntiles = qt + 1;

  const int tid = threadIdx.x, lane = tid & 63, wid = tid >> 6;
  const int c = lane & 15, q = lane >> 4;

  bf16x8 qf[2][4];
#pragma unroll
  for (int i = 0; i < 2; ++i) {
    int s = qt * 128 + wid * 32 + i * 16 + c;
    const u16* qrow = Qb + ((size_t)h * 2048 + s) * 128;
#pragma unroll
    for (int kc = 0; kc < 4; ++kc)
      qf[i][kc] = *(const bf16x8*)(qrow + kc * 32 + q * 8);
  }

  f32x4 oacc[2][8] = {};
  float lst[2][4] = {};

  auto STAGE = [&](int kt, int buf) {
    char* Kd = smem + buf * 32768;
    char* Vd = smem + buf * 32768 + 16384;
#pragma unroll
    for (int t = 0; t < 4; ++t) {
      int slot = (wid * 4 + t) * 64 + lane;
      int rowk = slot >> 4, csk = slot & 15;
      int cck = csk ^ (rowk & 7);
      const u16* gk = Kb + ((size_t)h * 2048 + kt * 64 + rowk) * 128 + cck * 8;
      gl_lds16(gk, Kd + (size_t)((wid * 4 + t) * 64) * 16);
      int rowv = slot >> 3, csv = slot & 7;
      int ccv = csv ^ (rowv & 7);
      const u16* gv = Vt + ((size_t)(h * 128 + rowv)) * 2048 + kt * 64 + ccv * 8;
      gl_lds16(gv, Vd + (size_t)((wid * 4 + t) * 64) * 16);
    }
  };

  STAGE(ktBase, 0);
  int cur = 0;

  for (int tt = 0; tt < ntiles; ++tt) {
    const int kt = ktBase + tt;
    if (tt + 1 < ntiles) {
      STAGE(kt + 1, cur ^ 1);
      __builtin_amdgcn_sched_barrier(0);
      asm volatile("s_waitcnt vmcnt(8)" ::: "memory");
    } else {
      asm volatile("s_waitcnt vmcnt(0)" ::: "memory");
    }
    __builtin_amdgcn_sched_barrier(0);
    bar();

    const char* Ksb = smem + cur * 32768;
    const char* Vsb = smem + cur * 32768 + 16384;

    f32x4 sacc[2][4] = {};
    __builtin_amdgcn_s_setprio(1);
#pragma unroll
    for (int kc = 0; kc < 4; ++kc) {
      bf16x8 bfr[4];
#pragma unroll
      for (int j = 0; j < 4; ++j) {
        int row = j * 16 + c;
        int ch = ((kc << 2) | q) ^ (row & 7);
        bfr[j] = *(const bf16x8*)(Ksb + row * 256 + ch * 16);
      }
#pragma unroll
      for (int i = 0; i < 2; ++i)
#pragma unroll
        for (int j = 0; j < 4; ++j)
          sacc[i][j] = mfma16(qf[i][kc], bfr[j], sacc[i][j]);
    }
    __builtin_amdgcn_s_setprio(0);
    bar();

    if (kt >= 2 * qt) {
#pragma unroll
      for (int i = 0; i < 2; ++i)
#pragma unroll
        for (int j = 0; j < 4; ++j) {
          int key = kt * 64 + j * 16 + c;
#pragma unroll
          for (int r = 0; r < 4; ++r) {
            int qrow = qt * 128 + wid * 32 + i * 16 + q * 4 + r;
            if (key > qrow) sacc[i][j][r] = -1e30f;
          }
        }
    }

#pragma unroll
    for (int i = 0; i < 2; ++i)
#pragma unroll
      for (int j = 0; j < 4; ++j)
#pragma unroll
        for (int r = 0; r < 4; ++r) {
          float p = __builtin_amdgcn_exp2f(sacc[i][j][r] * LOG2E);
          sacc[i][j][r] = p;
          lst[i][r] += p;
        }

    char* Pw = smem + cur * 32768 + wid * 4096;
#pragma unroll
    for (int i = 0; i < 2; ++i)
#pragma unroll
      for (int j = 0; j < 4; ++j) {
        uint32_t p01 = pk2(sacc[i][j][0], sacc[i][j][1]);
        uint32_t p23 = pk2(sacc[i][j][2], sacc[i][j][3]);
        int cb = (j << 1) | (c >> 3);
        int r0 = i * 16 + q * 4;
        int wb = (c & 7) << 1;
        *(u16*)(Pw + (r0 + 0) * 128 + ((cb ^ ((r0 + 0) & 7)) << 4) + wb) = (u16)p01;
        *(u16*)(Pw + (r0 + 1) * 128 + ((cb ^ ((r0 + 1) & 7)) << 4) + wb) = (u16)(p01 >> 16);
        *(u16*)(Pw + (r0 + 2) * 128 + ((cb ^ ((r0 + 2) & 7)) << 4) + wb) = (u16)p23;
        *(u16*)(Pw + (r0 + 3) * 128 + ((cb ^ ((r0 + 3) & 7)) << 4) + wb) = (u16)(p23 >> 16);
      }

    __builtin_amdgcn_s_setprio(1);
#pragma unroll
    for (int kc = 0; kc < 2; ++kc) {
      bf16x8 af[2], bv[8];
#pragma unroll
      for (int i = 0; i < 2; ++i) {
        int prow = i * 16 + c;
        af[i] = *(const bf16x8*)(Pw + prow * 128 + ((((kc << 2) | q) ^ (prow & 7)) << 4));
      }
#pragma unroll
      for (int jo = 0; jo < 8; ++jo) {
        int row = jo * 16 + c;
        int ch = ((kc << 2) | q) ^ (row & 7);
        bv[jo] = *(const bf16x8*)(Vsb + row * 128 + ch * 16);
      }
#pragma unroll
      for (int i = 0; i < 2; ++i)
#pragma unroll
        for (int jo = 0; jo < 8; ++jo)
          oacc[i][jo] = mfma16(bv[jo], af[i], oacc[i][jo]);
    }
    __builtin_amdgcn_s_setprio(0);
    bar();
    cur ^= 1;
  }

#pragma unroll
  for (int i = 0; i < 2; ++i)
#pragma unroll
    for (int r = 0; r < 4; ++r) {
      float l = lst[i][r];
      l += __shfl_xor(l, 1);
      l += __shfl_xor(l, 2);
      l += __shfl_xor(l, 4);
      l += __shfl_xor(l, 8);
      if (c == 0)
        lp[(size_t)h * 2048 + qt * 128 + wid * 32 + i * 16 + q * 4 + r] = l;
    }
#pragma unroll
  for (int i = 0; i < 2; ++i) {
    int s = qt * 128 + wid * 32 + i * 16 + c;
#pragma unroll
    for (int jo = 0; jo < 8; ++jo) {
      uint2 o;
      o.x = pk2(oacc[i][jo][0], oacc[i][jo][1]);
      o.y = pk2(oacc[i][jo][2], oacc[i][jo][3]);
      *(uint2*)(Op + ((size_t)h * 2048 + s) * 128 + jo * 16 + q * 4) = o;
    }
  }
}

// ---------------- combine: AO = (O0+O1)/(l0+l1), bf16 out [s][h*128+d] ----------------
__global__ void attn_combine(const u16* __restrict__ Opb, const float* __restrict__ lpb,
                             u16* __restrict__ AO) {
  int g = blockIdx.x * 256 + threadIdx.x;
  int row = g >> 4;
  int dd = (g & 15) * 8;
  int h = row >> 11, s = row & 2047;
  float inv = 1.0f / (lpb[row] + lpb[row + 32768]);
  uint4 a = *(const uint4*)(Opb + (size_t)row * 128 + dd);
  uint4 bb = *(const uint4*)(Opb + 4194304 + (size_t)row * 128 + dd);
  const u16* pa = (const u16*)&a;
  const u16* pb = (const u16*)&bb;
  uint4 res;
  uint32_t* pr = (uint32_t*)&res;
#pragma unroll
  for (int t = 0; t < 4; ++t)
    pr[t] = pk2((bf2f(pa[2 * t]) + bf2f(pb[2 * t])) * inv,
                (bf2f(pa[2 * t + 1]) + bf2f(pb[2 * t + 1])) * inv);
  *(uint4*)(AO + (size_t)s * 2048 + h * 128 + dd) = res;
}

extern "C" void kernel_launch(void* const* d_in, const int* in_sizes, int n_in,
                              void* d_out, int out_size, void* d_ws, size_t ws_size,
                              hipStream_t stream) {
  const float* x  = (const float*)d_in[0];
  const float* Wq = (const float*)d_in[1];
  const float* bq = (const float*)d_in[2];
  const float* Wk = (const float*)d_in[3];
  const float* bk = (const float*)d_in[4];
  const float* Wv = (const float*)d_in[5];
  const float* bv = (const float*)d_in[6];
  const float* Wo = (const float*)d_in[7];
  const float* bo = (const float*)d_in[8];

  char* ws = (char*)d_ws;
  u16* xb = (u16*)(ws);                          // x bf16            0- 8 MB
  u16* wt = (u16*)(ws + (size_t)8  * 1048576);   // Wq/k/v/o^T bf16   8-40 MB
  u16* Qb = (u16*)(ws + (size_t)40 * 1048576);   // Q [h][s][d]      40-48 MB
  u16* Kb = (u16*)(ws + (size_t)48 * 1048576);   // K [h][s][d]      48-56 MB
  u16* Vt = (u16*)(ws + (size_t)56 * 1048576);   // V^T [h][d][s]    56-64 MB
  u16* AO = (u16*)(ws + (size_t)64 * 1048576);   // attn out [s][D]  64-72 MB
  u16* Opb = (u16*)(ws);
  float* lpb = (float*)d_out;

  static bool inited = false;
  if (!inited) {
    hipFuncSetAttribute((const void*)gemm_qkv,
                        hipFuncAttributeMaxDynamicSharedMemorySize, 131072);
    inited = true;
  }

  cvt_bf16<<<4096, 256, 0, stream>>>(x, xb);
  transpose_cvt<<<dim3(32, 32, 4), 256, 0, stream>>>(Wq, Wk, Wv, Wo, wt);
  gemm_qkv<<<192, 512, 131072, stream>>>(xb, wt, bq, bk, bv, Qb, Kb, Vt);
  attn_kernel<<<512, 256, 65536, stream>>>(Qb, Kb, Vt, Opb, lpb);
  attn_combine<<<2048, 256, 0, stream>>>(Opb, lpb, AO);
  gemm_op<<<dim3(32, 16), 256, 24576, stream>>>(AO, wt + (size_t)3 * 2048 * 2048,
                                                bo, (float*)d_out);
}

// Round 3
// 259.553 us; speedup vs baseline: 1.1701x; 1.1701x over previous
//
#include <hip/hip_runtime.h>
#include <hip/hip_bf16.h>
#include <stdint.h>

typedef unsigned short u16;
typedef __attribute__((ext_vector_type(8))) __bf16 bf16x8;
typedef __attribute__((ext_vector_type(4))) float f32x4;

#define LOG2E 1.4426950408889634f

__device__ __forceinline__ float bf2f(u16 u) {
  union { uint32_t u; float f; } v; v.u = ((uint32_t)u) << 16;
  return v.f;
}

// packed cvt: two fp32 -> one u32 holding (lo=a, hi=b) bf16
__device__ __forceinline__ uint32_t pk2(float a, float b) {
  union { __hip_bfloat162 h; uint32_t u; } x;
  x.h = __float22bfloat162_rn(make_float2(a, b));
  return x.u;
}

__device__ __forceinline__ void gl_lds16(const void* g, void* l) {
  __builtin_amdgcn_global_load_lds((const __attribute__((address_space(1))) void*)g,
                                   (__attribute__((address_space(3))) void*)l,
                                   16, 0, 0);
}

__device__ __forceinline__ f32x4 mfma16(bf16x8 a, bf16x8 b, f32x4 c) {
  return __builtin_amdgcn_mfma_f32_16x16x32_bf16(a, b, c, 0, 0, 0);
}

// raw workgroup barrier with compiler memory fence (no vmcnt/lgkm drain)
__device__ __forceinline__ void bar() {
  asm volatile("" ::: "memory");
  __builtin_amdgcn_s_barrier();
  asm volatile("" ::: "memory");
}

// ---------------- fp32 -> bf16 elementwise (x) ----------------
__global__ void cvt_bf16(const float* __restrict__ src, u16* __restrict__ dst) {
  int i = (blockIdx.x * 256 + threadIdx.x) * 4;
  float4 f = *(const float4*)(src + i);
  uint2 o;
  o.x = pk2(f.x, f.y);
  o.y = pk2(f.z, f.w);
  *(uint2*)(dst + i) = o;
}

// ---------------- transpose + convert: W[k][n] fp32 -> Wt[n][k] bf16 ----------------
__global__ void transpose_cvt(const float* __restrict__ W0, const float* __restrict__ W1,
                              const float* __restrict__ W2, const float* __restrict__ W3,
                              u16* __restrict__ out) {
  __shared__ float tile[64][65];
  int z = blockIdx.z;
  const float* W = (z == 0) ? W0 : (z == 1) ? W1 : (z == 2) ? W2 : W3;
  u16* dst = out + (size_t)z * 2048 * 2048;
  int k0 = blockIdx.y * 64, n0 = blockIdx.x * 64;
  int lx = threadIdx.x & 63, ly = threadIdx.x >> 6;
#pragma unroll
  for (int p = 0; p < 16; ++p) {
    int row = p * 4 + ly;
    tile[row][lx] = W[(size_t)(k0 + row) * 2048 + n0 + lx];
  }
  __syncthreads();
  int kc = threadIdx.x & 7;        // 8-wide k chunk
  int rbase = threadIdx.x >> 3;    // 0..31
#pragma unroll
  for (int p = 0; p < 2; ++p) {
    int n = rbase + p * 32;        // n-local row
    uint4 o;
    o.x = pk2(tile[kc * 8 + 0][n], tile[kc * 8 + 1][n]);
    o.y = pk2(tile[kc * 8 + 2][n], tile[kc * 8 + 3][n]);
    o.z = pk2(tile[kc * 8 + 4][n], tile[kc * 8 + 5][n]);
    o.w = pk2(tile[kc * 8 + 6][n], tile[kc * 8 + 7][n]);
    *(uint4*)(dst + (size_t)(n0 + n) * 2048 + k0 + kc * 8) = o;
  }
}

// ---------------- QKV GEMM: 256x256 tile, 8 waves, counted-vmcnt 4-phase pipeline ----
// REPAIRED from round 2: LDS half-tile units now use gemm_bt's PROVEN conflict-free
// layout ([128 rows][8 chunks of 16B], chunk = k ^ (row&7), 128B row stride; measured
// 98K conflicts vs 4.78M for the 64B-row layout). Phase p = C-quadrant (mh,nh) of the
// 256x256 tile; 8 waves split each 128x128 quadrant 2Mx4N (per-wave 64x32 per phase).
// Each phase reads exactly ONE A-unit (mh) + ONE B-unit (nh).
// Units per K-tile in issue order {A0,B0,B1,A1}; phase needs: p0{A0,B0} p1{A0,B1}
// p2{A1,B0} p3{A1,B1}. Stage 1 unit/phase, one tile ahead (write buf = read buf ^ 1,
// race-free with per-phase barrier). Counted waits per phase: vmcnt(4)/(4)/(4)/(6),
// ledger: at phase j of tile t, issued-through unit 4t+3+j, wait leaves {2,2,2,3}[j]
// units in flight -> completed through exactly the unit phase j needs. Full drain
// vmcnt(0) only at the last tile's first phase.
__launch_bounds__(512, 2)
__global__ void gemm_qkv(const u16* __restrict__ A, const u16* __restrict__ Bt,
                         const float* __restrict__ b0, const float* __restrict__ b1,
                         const float* __restrict__ b2,
                         u16* __restrict__ outQ, u16* __restrict__ outK,
                         u16* __restrict__ outVT) {
  extern __shared__ char smem[];
  const int K = 2048, NT = 32;
  const int tid = threadIdx.x;
  const int lane = tid & 63, wid = tid >> 6;
  const int c = lane & 15, q = lane >> 4;
  const int wm = wid >> 2, wn = wid & 3;   // 2M x 4N within each 128x128 quadrant
  // XCD-aware swizzle: XCD x owns tm = x (A-panel 1 MB L2-resident); 192 % 8 == 0
  int raw = blockIdx.x;
  int sbid = (raw & 7) * 24 + (raw >> 3);
  const int tm = sbid / 24, tn = sbid % 24;
  const size_t Abase = (size_t)tm * 256 * K;
  const size_t Bbase = (size_t)tn * 256 * K;

  f32x4 acc[4][4][2] = {};   // [quadrant p][i (16-row frag)][j (16-col frag)]

  // stage issue-unit uj of tile t2 into buf (t2&1).
  // uj: 0=A half0, 1=B half0, 2=B half1, 3=A half1. LDS regions: A0,A1,B0,B1.
  auto STAGE = [&](int t2, int uj) {
    const int isB = (uj == 1 || uj == 2);
    const int half = (uj >= 2) ? 1 : 0;
    const int reg = isB ? (2 + half) : half;
    char* dst = smem + (t2 & 1) * 65536 + reg * 16384;
    const u16* src = (isB ? (Bt + Bbase) : (A + Abase)) + (size_t)(half * 128) * K;
#pragma unroll
    for (int l = 0; l < 2; ++l) {
      int s = l * 512 + tid;           // slot 0..1023 (16B each)
      int r = s >> 3, cs = s & 7;
      int cc = cs ^ (r & 7);
      gl_lds16(src + (size_t)r * K + t2 * 64 + cc * 8, dst + (size_t)s * 16);
    }
  };

#define PH(J)                                                                     \
  {                                                                               \
    if (t == NT - 1) {                                                            \
      if ((J) == 0) asm volatile("s_waitcnt vmcnt(0)" ::: "memory");              \
    } else if ((J) == 3) {                                                        \
      asm volatile("s_waitcnt vmcnt(6)" ::: "memory");                            \
    } else {                                                                      \
      asm volatile("s_waitcnt vmcnt(4)" ::: "memory");                            \
    }                                                                             \
    __builtin_amdgcn_sched_barrier(0);                                            \
    bar();                                                                        \
    if (t + 1 < NT) STAGE(t + 1, (J));                                            \
    const int mh = (J) >> 1, nh = (J) & 1;                                        \
    const char* Ab = smem + buf * 65536 + mh * 16384;                             \
    const char* Bb = smem + buf * 65536 + (2 + nh) * 16384;                       \
    _Pragma("unroll") for (int kc = 0; kc < 2; ++kc) {                            \
      bf16x8 af[4], bf[2];                                                        \
      _Pragma("unroll") for (int i = 0; i < 4; ++i) {                             \
        int row = wm * 64 + i * 16 + c;                                           \
        af[i] = *(const bf16x8*)(Ab + row * 128 + ((((kc << 2) | q) ^ (row & 7)) << 4)); \
      }                                                                           \
      _Pragma("unroll") for (int j = 0; j < 2; ++j) {                             \
        int row = wn * 32 + j * 16 + c;                                           \
        bf[j] = *(const bf16x8*)(Bb + row * 128 + ((((kc << 2) | q) ^ (row & 7)) << 4)); \
      }                                                                           \
      __builtin_amdgcn_s_setprio(1);                                              \
      _Pragma("unroll") for (int i = 0; i < 4; ++i)                               \
        _Pragma("unroll") for (int j = 0; j < 2; ++j)                             \
          acc[(J)][i][j] = mfma16(af[i], bf[j], acc[(J)][i][j]);                  \
      __builtin_amdgcn_s_setprio(0);                                              \
    }                                                                             \
  }

  // prologue: tile 0's 4 units in issue order
  STAGE(0, 0); STAGE(0, 1); STAGE(0, 2); STAGE(0, 3);

#pragma unroll 2
  for (int t = 0; t < NT; ++t) {
    const int buf = t & 1;
    PH(0) PH(1) PH(2) PH(3)
  }
#undef PH

  // ---- epilogue ----
  const int proj = tn >> 3;
  const int tnp = tn & 7;          // tile within projection; heads tnp*2 + nh
  if (proj < 2) {
    u16* out = (proj == 0) ? outQ : outK;
    const float* bias = (proj == 0) ? b0 : b1;
    const float scale = (proj == 0) ? 0.08838834764831845f : 1.0f;
#pragma unroll
    for (int p = 0; p < 4; ++p) {
      int h = tnp * 2 + (p & 1);
#pragma unroll
      for (int i = 0; i < 4; ++i) {
        int s0 = tm * 256 + (p >> 1) * 128 + wm * 64 + i * 16 + q * 4;
#pragma unroll
        for (int j = 0; j < 2; ++j) {
          int d = wn * 32 + j * 16 + c;
          float bv = bias[h * 128 + d];
          uint32_t p01 = pk2((acc[p][i][j][0] + bv) * scale, (acc[p][i][j][1] + bv) * scale);
          uint32_t p23 = pk2((acc[p][i][j][2] + bv) * scale, (acc[p][i][j][3] + bv) * scale);
          u16* o = out + ((size_t)h * 2048 + s0) * 128 + d;
          o[0]   = (u16)p01;
          o[128] = (u16)(p01 >> 16);
          o[256] = (u16)p23;
          o[384] = (u16)(p23 >> 16);
        }
      }
    }
  } else {
    // V: transpose via LDS -> Vt[h][d][s]; one pass per head (nh) of this tile
    u16* Cs = (u16*)smem;   // [128 d][264 s-padded] u16 = 67.5 KB
#pragma unroll
    for (int hh = 0; hh < 2; ++hh) {
      bar();   // prior reads (K-loop tail / pass hh-1) complete before overwrite
#pragma unroll
      for (int pp = 0; pp < 2; ++pp) {
        int p = pp * 2 + hh;           // quadrants with nh == hh; mh = pp
#pragma unroll
        for (int i = 0; i < 4; ++i) {
          int sl = pp * 128 + wm * 64 + i * 16 + q * 4;
#pragma unroll
          for (int j = 0; j < 2; ++j) {
            int dl = wn * 32 + j * 16 + c;
            float bv = b2[tnp * 256 + hh * 128 + dl];
            uint2 pk;
            pk.x = pk2(acc[p][i][j][0] + bv, acc[p][i][j][1] + bv);
            pk.y = pk2(acc[p][i][j][2] + bv, acc[p][i][j][3] + bv);
            *(uint2*)(Cs + dl * 264 + sl) = pk;
          }
        }
      }
      bar();
#pragma unroll
      for (int kk = 0; kk < 8; ++kk) {
        int cid = kk * 512 + tid;
        int d = cid >> 5, sc = (cid & 31) * 8;
        uint4 vv = *(const uint4*)(Cs + d * 264 + sc);
        *(uint4*)(outVT + ((size_t)((tnp * 2 + hh) * 128 + d)) * 2048 + tm * 256 + sc) = vv;
      }
    }
  }
}

// ---------------- O-projection GEMM: 128x64 tiles for co-residency ----------------
__launch_bounds__(256, 2)
__global__ void gemm_op(const u16* __restrict__ A, const u16* __restrict__ Bt,
                        const float* __restrict__ bias, float* __restrict__ out) {
  extern __shared__ char smem[];
  u16* As = (u16*)smem;              // [128][64]  16 KB
  u16* Bs = (u16*)(smem + 16384);    // [64][64]    8 KB
  const int K = 2048;
  const int tid = threadIdx.x;
  const int lane = tid & 63, wid = tid >> 6;
  const int c = lane & 15, q = lane >> 4;
  const int wm = wid >> 1, wn = wid & 1;
  const int tm = blockIdx.y, tn = blockIdx.x;
  const size_t Abase = (size_t)tm * 128 * K;
  const size_t Bbase = (size_t)tn * 64 * K;

  f32x4 acc[4][2] = {};

  for (int kt = 0; kt < K / 64; ++kt) {
#pragma unroll
    for (int t = 0; t < 4; ++t) {
      int slot = wid * 256 + t * 64 + lane;
      int row = slot >> 3, cs = slot & 7;
      int cc = cs ^ (row & 7);
      gl_lds16(A + Abase + (size_t)row * K + kt * 64 + cc * 8,
               (char*)As + (size_t)(wid * 256 + t * 64) * 16);
    }
#pragma unroll
    for (int t = 0; t < 2; ++t) {
      int slot = wid * 128 + t * 64 + lane;
      int row = slot >> 3, cs = slot & 7;
      int cc = cs ^ (row & 7);
      gl_lds16(Bt + Bbase + (size_t)row * K + kt * 64 + cc * 8,
               (char*)Bs + (size_t)(wid * 128 + t * 64) * 16);
    }
    __syncthreads();
#pragma unroll
    for (int kc = 0; kc < 2; ++kc) {
      bf16x8 af[4], bfr[2];
#pragma unroll
      for (int i = 0; i < 4; ++i) {
        int rowa = wm * 64 + i * 16 + c;
        int cha = ((kc << 2) | q) ^ (rowa & 7);
        af[i] = *(const bf16x8*)((const char*)As + rowa * 128 + cha * 16);
      }
#pragma unroll
      for (int j = 0; j < 2; ++j) {
        int rowb = wn * 32 + j * 16 + c;
        int chb = ((kc << 2) | q) ^ (rowb & 7);
        bfr[j] = *(const bf16x8*)((const char*)Bs + rowb * 128 + chb * 16);
      }
#pragma unroll
      for (int i = 0; i < 4; ++i)
#pragma unroll
        for (int j = 0; j < 2; ++j)
          acc[i][j] = mfma16(af[i], bfr[j], acc[i][j]);
    }
    __syncthreads();
  }

#pragma unroll
  for (int i = 0; i < 4; ++i) {
    int rowg = tm * 128 + wm * 64 + i * 16 + q * 4;
#pragma unroll
    for (int j = 0; j < 2; ++j) {
      int colg = tn * 64 + wn * 32 + j * 16 + c;
      float bv = bias[colg];
#pragma unroll
      for (int r = 0; r < 4; ++r)
        out[(size_t)(rowg + r) * 2048 + colg] = acc[i][j][r] + bv;
    }
  }
}

// ---------------- flash attention, causal, split-K(2), max-free softmax ----------------
// Double-buffered K/V staging with counted vmcnt(8); P slab reuses the dead current
// K buffer after the QK^T barrier. Raw s_barrier (no vmcnt drain). 2 blocks/CU.
// Stores RAW partial O (bf16) + row-sum l (fp32 in d_out scratch); combine divides
// by (l0+l1). qt=0/split1 has l=0,O=0 rows — benign raw; NEVER normalize per-split.
__launch_bounds__(256, 2)
__global__ void attn_kernel(const u16* __restrict__ Qb, const u16* __restrict__ Kb,
                            const u16* __restrict__ Vt,
                            u16* __restrict__ Opb, float* __restrict__ lpb) {
  extern __shared__ char smem[];
  int b = blockIdx.x;
  int split, qt, h;
  if (b < 256) { split = 0; qt = b >> 4; h = b & 15; }
  else { split = 1; int idx = b - 256; qt = 15 - (idx >> 4); h = idx & 15; }
  u16* Op = Opb + (size_t)split * 4194304;
  float* lp = lpb + (size_t)split * 32768;
  const int ktBase = split ? (qt + 1) : 0;
  const int ntiles = qt + 1;

  const int tid = threadIdx.x, lane = tid & 63, wid = tid >> 6;
  const int c = lane & 15, q = lane >> 4;

  bf16x8 qf[2][4];
#pragma unroll
  for (int i = 0; i < 2; ++i) {
    int s = qt * 128 + wid * 32 + i * 16 + c;
    const u16* qrow = Qb + ((size_t)h * 2048 + s) * 128;
#pragma unroll
    for (int kc = 0; kc < 4; ++kc)
      qf[i][kc] = *(const bf16x8*)(qrow + kc * 32 + q * 8);
  }

  f32x4 oacc[2][8] = {};
  float lst[2][4] = {};

  auto STAGE = [&](int kt, int buf) {
    char* Kd = smem + buf * 32768;
    char* Vd = smem + buf * 32768 + 16384;
#pragma unroll
    for (int t = 0; t < 4; ++t) {
      int slot = (wid * 4 + t) * 64 + lane;
      int rowk = slot >> 4, csk = slot & 15;
      int cck = csk ^ (rowk & 7);
      const u16* gk = Kb + ((size_t)h * 2048 + kt * 64 + rowk) * 128 + cck * 8;
      gl_lds16(gk, Kd + (size_t)((wid * 4 + t) * 64) * 16);
      int rowv = slot >> 3, csv = slot & 7;
      int ccv = csv ^ (rowv & 7);
      const u16* gv = Vt + ((size_t)(h * 128 + rowv)) * 2048 + kt * 64 + ccv * 8;
      gl_lds16(gv, Vd + (size_t)((wid * 4 + t) * 64) * 16);
    }
  };

  STAGE(ktBase, 0);
  int cur = 0;

  for (int tt = 0; tt < ntiles; ++tt) {
    const int kt = ktBase + tt;
    if (tt + 1 < ntiles) {
      STAGE(kt + 1, cur ^ 1);
      __builtin_amdgcn_sched_barrier(0);
      asm volatile("s_waitcnt vmcnt(8)" ::: "memory");
    } else {
      asm volatile("s_waitcnt vmcnt(0)" ::: "memory");
    }
    __builtin_amdgcn_sched_barrier(0);
    bar();

    const char* Ksb = smem + cur * 32768;
    const char* Vsb = smem + cur * 32768 + 16384;

    f32x4 sacc[2][4] = {};
    __builtin_amdgcn_s_setprio(1);
#pragma unroll
    for (int kc = 0; kc < 4; ++kc) {
      bf16x8 bfr[4];
#pragma unroll
      for (int j = 0; j < 4; ++j) {
        int row = j * 16 + c;
        int ch = ((kc << 2) | q) ^ (row & 7);
        bfr[j] = *(const bf16x8*)(Ksb + row * 256 + ch * 16);
      }
#pragma unroll
      for (int i = 0; i < 2; ++i)
#pragma unroll
        for (int j = 0; j < 4; ++j)
          sacc[i][j] = mfma16(qf[i][kc], bfr[j], sacc[i][j]);
    }
    __builtin_amdgcn_s_setprio(0);
    bar();

    if (kt >= 2 * qt) {
#pragma unroll
      for (int i = 0; i < 2; ++i)
#pragma unroll
        for (int j = 0; j < 4; ++j) {
          int key = kt * 64 + j * 16 + c;
#pragma unroll
          for (int r = 0; r < 4; ++r) {
            int qrow = qt * 128 + wid * 32 + i * 16 + q * 4 + r;
            if (key > qrow) sacc[i][j][r] = -1e30f;
          }
        }
    }

#pragma unroll
    for (int i = 0; i < 2; ++i)
#pragma unroll
      for (int j = 0; j < 4; ++j)
#pragma unroll
        for (int r = 0; r < 4; ++r) {
          float p = __builtin_amdgcn_exp2f(sacc[i][j][r] * LOG2E);
          sacc[i][j][r] = p;
          lst[i][r] += p;
        }

    char* Pw = smem + cur * 32768 + wid * 4096;
#pragma unroll
    for (int i = 0; i < 2; ++i)
#pragma unroll
      for (int j = 0; j < 4; ++j) {
        uint32_t p01 = pk2(sacc[i][j][0], sacc[i][j][1]);
        uint32_t p23 = pk2(sacc[i][j][2], sacc[i][j][3]);
        int cb = (j << 1) | (c >> 3);
        int r0 = i * 16 + q * 4;
        int wb = (c & 7) << 1;
        *(u16*)(Pw + (r0 + 0) * 128 + ((cb ^ ((r0 + 0) & 7)) << 4) + wb) = (u16)p01;
        *(u16*)(Pw + (r0 + 1) * 128 + ((cb ^ ((r0 + 1) & 7)) << 4) + wb) = (u16)(p01 >> 16);
        *(u16*)(Pw + (r0 + 2) * 128 + ((cb ^ ((r0 + 2) & 7)) << 4) + wb) = (u16)p23;
        *(u16*)(Pw + (r0 + 3) * 128 + ((cb ^ ((r0 + 3) & 7)) << 4) + wb) = (u16)(p23 >> 16);
      }

    __builtin_amdgcn_s_setprio(1);
#pragma unroll
    for (int kc = 0; kc < 2; ++kc) {
      bf16x8 af[2], bv[8];
#pragma unroll
      for (int i = 0; i < 2; ++i) {
        int prow = i * 16 + c;
        af[i] = *(const bf16x8*)(Pw + prow * 128 + ((((kc << 2) | q) ^ (prow & 7)) << 4));
      }
#pragma unroll
      for (int jo = 0; jo < 8; ++jo) {
        int row = jo * 16 + c;
        int ch = ((kc << 2) | q) ^ (row & 7);
        bv[jo] = *(const bf16x8*)(Vsb + row * 128 + ch * 16);
      }
#pragma unroll
      for (int i = 0; i < 2; ++i)
#pragma unroll
        for (int jo = 0; jo < 8; ++jo)
          oacc[i][jo] = mfma16(bv[jo], af[i], oacc[i][jo]);
    }
    __builtin_amdgcn_s_setprio(0);
    bar();
    cur ^= 1;
  }

#pragma unroll
  for (int i = 0; i < 2; ++i)
#pragma unroll
    for (int r = 0; r < 4; ++r) {
      float l = lst[i][r];
      l += __shfl_xor(l, 1);
      l += __shfl_xor(l, 2);
      l += __shfl_xor(l, 4);
      l += __shfl_xor(l, 8);
      if (c == 0)
        lp[(size_t)h * 2048 + qt * 128 + wid * 32 + i * 16 + q * 4 + r] = l;
    }
#pragma unroll
  for (int i = 0; i < 2; ++i) {
    int s = qt * 128 + wid * 32 + i * 16 + c;
#pragma unroll
    for (int jo = 0; jo < 8; ++jo) {
      uint2 o;
      o.x = pk2(oacc[i][jo][0], oacc[i][jo][1]);
      o.y = pk2(oacc[i][jo][2], oacc[i][jo][3]);
      *(uint2*)(Op + ((size_t)h * 2048 + s) * 128 + jo * 16 + q * 4) = o;
    }
  }
}

// ---------------- combine: AO = (O0+O1)/(l0+l1), bf16 out [s][h*128+d] ----------------
__global__ void attn_combine(const u16* __restrict__ Opb, const float* __restrict__ lpb,
                             u16* __restrict__ AO) {
  int g = blockIdx.x * 256 + threadIdx.x;
  int row = g >> 4;
  int dd = (g & 15) * 8;
  int h = row >> 11, s = row & 2047;
  float inv = 1.0f / (lpb[row] + lpb[row + 32768]);
  uint4 a = *(const uint4*)(Opb + (size_t)row * 128 + dd);
  uint4 bb = *(const uint4*)(Opb + 4194304 + (size_t)row * 128 + dd);
  const u16* pa = (const u16*)&a;
  const u16* pb = (const u16*)&bb;
  uint4 res;
  uint32_t* pr = (uint32_t*)&res;
#pragma unroll
  for (int t = 0; t < 4; ++t)
    pr[t] = pk2((bf2f(pa[2 * t]) + bf2f(pb[2 * t])) * inv,
                (bf2f(pa[2 * t + 1]) + bf2f(pb[2 * t + 1])) * inv);
  *(uint4*)(AO + (size_t)s * 2048 + h * 128 + dd) = res;
}

extern "C" void kernel_launch(void* const* d_in, const int* in_sizes, int n_in,
                              void* d_out, int out_size, void* d_ws, size_t ws_size,
                              hipStream_t stream) {
  const float* x  = (const float*)d_in[0];
  const float* Wq = (const float*)d_in[1];
  const float* bq = (const float*)d_in[2];
  const float* Wk = (const float*)d_in[3];
  const float* bk = (const float*)d_in[4];
  const float* Wv = (const float*)d_in[5];
  const float* bv = (const float*)d_in[6];
  const float* Wo = (const float*)d_in[7];
  const float* bo = (const float*)d_in[8];

  char* ws = (char*)d_ws;
  u16* xb = (u16*)(ws);                          // x bf16            0- 8 MB
  u16* wt = (u16*)(ws + (size_t)8  * 1048576);   // Wq/k/v/o^T bf16   8-40 MB
  u16* Qb = (u16*)(ws + (size_t)40 * 1048576);   // Q [h][s][d]      40-48 MB
  u16* Kb = (u16*)(ws + (size_t)48 * 1048576);   // K [h][s][d]      48-56 MB
  u16* Vt = (u16*)(ws + (size_t)56 * 1048576);   // V^T [h][d][s]    56-64 MB
  u16* AO = (u16*)(ws + (size_t)64 * 1048576);   // attn out [s][D]  64-72 MB
  u16* Opb = (u16*)(ws);
  float* lpb = (float*)d_out;

  static bool inited = false;
  if (!inited) {
    hipFuncSetAttribute((const void*)gemm_qkv,
                        hipFuncAttributeMaxDynamicSharedMemorySize, 131072);
    inited = true;
  }

  cvt_bf16<<<4096, 256, 0, stream>>>(x, xb);
  transpose_cvt<<<dim3(32, 32, 4), 256, 0, stream>>>(Wq, Wk, Wv, Wo, wt);
  gemm_qkv<<<192, 512, 131072, stream>>>(xb, wt, bq, bk, bv, Qb, Kb, Vt);
  attn_kernel<<<512, 256, 65536, stream>>>(Qb, Kb, Vt, Opb, lpb);
  attn_combine<<<2048, 256, 0, stream>>>(Opb, lpb, AO);
  gemm_op<<<dim3(32, 16), 256, 24576, stream>>>(AO, wt + (size_t)3 * 2048 * 2048,
                                                bo, (float*)d_out);
}

// Round 4
// 255.016 us; speedup vs baseline: 1.1909x; 1.0178x over previous
//
#include <hip/hip_runtime.h>
#include <hip/hip_bf16.h>
#include <stdint.h>

typedef unsigned short u16;
typedef __attribute__((ext_vector_type(8))) __bf16 bf16x8;
typedef __attribute__((ext_vector_type(4))) float f32x4;

#define LOG2E 1.4426950408889634f

__device__ __forceinline__ float bf2f(u16 u) {
  union { uint32_t u; float f; } v; v.u = ((uint32_t)u) << 16;
  return v.f;
}

// packed cvt: two fp32 -> one u32 holding (lo=a, hi=b) bf16
__device__ __forceinline__ uint32_t pk2(float a, float b) {
  union { __hip_bfloat162 h; uint32_t u; } x;
  x.h = __float22bfloat162_rn(make_float2(a, b));
  return x.u;
}

__device__ __forceinline__ void gl_lds16(const void* g, void* l) {
  __builtin_amdgcn_global_load_lds((const __attribute__((address_space(1))) void*)g,
                                   (__attribute__((address_space(3))) void*)l,
                                   16, 0, 0);
}

__device__ __forceinline__ f32x4 mfma16(bf16x8 a, bf16x8 b, f32x4 c) {
  return __builtin_amdgcn_mfma_f32_16x16x32_bf16(a, b, c, 0, 0, 0);
}

// raw workgroup barrier with compiler memory fence (no vmcnt/lgkm drain)
__device__ __forceinline__ void bar() {
  asm volatile("" ::: "memory");
  __builtin_amdgcn_s_barrier();
  asm volatile("" ::: "memory");
}

// ---------------- fused preprocessing ----------------
// z<4: transpose+cvt W_z[k][n] fp32 -> Wt[n][k] bf16 (grid (32,32) per z)
// z==4: x fp32 -> bf16 elementwise (1024 logical blocks via (y*32+x), 16 floats/thread)
__global__ void prep_kernel(const float* __restrict__ W0, const float* __restrict__ W1,
                            const float* __restrict__ W2, const float* __restrict__ W3,
                            u16* __restrict__ wout,
                            const float* __restrict__ xsrc, u16* __restrict__ xdst) {
  int z = blockIdx.z;
  if (z == 4) {
    int lin = blockIdx.y * 32 + blockIdx.x;   // 0..1023
    int tid = threadIdx.x;
#pragma unroll
    for (int p = 0; p < 4; ++p) {
      int i4 = (lin * 4 + p) * 256 + tid;     // float4 index, coalesced per pass
      float4 f = *(const float4*)(xsrc + (size_t)i4 * 4);
      uint2 o;
      o.x = pk2(f.x, f.y);
      o.y = pk2(f.z, f.w);
      *(uint2*)(xdst + (size_t)i4 * 4) = o;
    }
    return;
  }
  __shared__ float tile[64][65];
  const float* W = (z == 0) ? W0 : (z == 1) ? W1 : (z == 2) ? W2 : W3;
  u16* dst = wout + (size_t)z * 2048 * 2048;
  int k0 = blockIdx.y * 64, n0 = blockIdx.x * 64;
  int lx = threadIdx.x & 63, ly = threadIdx.x >> 6;
#pragma unroll
  for (int p = 0; p < 16; ++p) {
    int row = p * 4 + ly;
    tile[row][lx] = W[(size_t)(k0 + row) * 2048 + n0 + lx];
  }
  __syncthreads();
  int kc = threadIdx.x & 7;        // 8-wide k chunk
  int rbase = threadIdx.x >> 3;    // 0..31
#pragma unroll
  for (int p = 0; p < 2; ++p) {
    int n = rbase + p * 32;        // n-local row
    uint4 o;
    o.x = pk2(tile[kc * 8 + 0][n], tile[kc * 8 + 1][n]);
    o.y = pk2(tile[kc * 8 + 2][n], tile[kc * 8 + 3][n]);
    o.z = pk2(tile[kc * 8 + 4][n], tile[kc * 8 + 5][n]);
    o.w = pk2(tile[kc * 8 + 6][n], tile[kc * 8 + 7][n]);
    *(uint4*)(dst + (size_t)(n0 + n) * 2048 + k0 + kc * 8) = o;
  }
}

// ---------------- bf16 GEMM, m97-style (PROVEN 55.3 us): QKV projections ----------------
// 1D grid 768, XCD-aware B-resident swizzle: XCD x owns tn in [6x,6x+6) (6 B-panels =
// 3 MB, L2-resident) and streams all A (8 MB, L3-served). 768 % 8 == 0 -> bijective.
// tn in [0,48): proj=tn>>4, h=tn&15
//   proj 0: Q[h][s][d] = (acc+bq)/sqrt(128); proj 1: K[h][s][d]; proj 2: Vt[h][d][s]
__launch_bounds__(256, 2)
__global__ void gemm_bt(const u16* __restrict__ A, const u16* __restrict__ Bt,
                        const float* __restrict__ b0, const float* __restrict__ b1,
                        const float* __restrict__ b2,
                        u16* __restrict__ outQ, u16* __restrict__ outK,
                        u16* __restrict__ outVT) {
  extern __shared__ char smem[];
  u16* As = (u16*)smem;              // [128][64] bf16, 16B-chunk XOR swizzled
  u16* Bs = (u16*)(smem + 16384);
  const int K = 2048;
  const int tid = threadIdx.x;
  const int lane = tid & 63, wid = tid >> 6;
  const int c = lane & 15, q = lane >> 4;
  const int wm = wid >> 1, wn = wid & 1;
  // XCD swizzle: bid%8 = XCD (round-robin dispatch); give each XCD 6 tn cols x 16 tm
  const int bid = blockIdx.x;
  const int xcd = bid & 7, idx = bid >> 3;     // idx 0..95
  const int tn = xcd * 6 + idx % 6;
  const int tm = idx / 6;
  const size_t Abase = (size_t)tm * 128 * K;
  const size_t Bbase = (size_t)tn * 128 * K;

  f32x4 acc[4][4] = {};

  for (int kt = 0; kt < K / 64; ++kt) {
#pragma unroll
    for (int t = 0; t < 4; ++t) {
      int slot = wid * 256 + t * 64 + lane;
      int row = slot >> 3, cs = slot & 7;
      int cc = cs ^ (row & 7);
      const u16* ga = A + Abase + (size_t)row * K + kt * 64 + cc * 8;
      gl_lds16(ga, (char*)As + (size_t)(wid * 256 + t * 64) * 16);
      const u16* gb = Bt + Bbase + (size_t)row * K + kt * 64 + cc * 8;
      gl_lds16(gb, (char*)Bs + (size_t)(wid * 256 + t * 64) * 16);
    }
    __syncthreads();
#pragma unroll
    for (int kc = 0; kc < 2; ++kc) {
      bf16x8 af[4], bfr[4];
#pragma unroll
      for (int i = 0; i < 4; ++i) {
        int rowa = wm * 64 + i * 16 + c;
        int cha = ((kc << 2) | q) ^ (rowa & 7);
        af[i] = *(const bf16x8*)((const char*)As + rowa * 128 + cha * 16);
        int rowb = wn * 64 + i * 16 + c;
        int chb = ((kc << 2) | q) ^ (rowb & 7);
        bfr[i] = *(const bf16x8*)((const char*)Bs + rowb * 128 + chb * 16);
      }
#pragma unroll
      for (int i = 0; i < 4; ++i)
#pragma unroll
        for (int j = 0; j < 4; ++j)
          acc[i][j] = mfma16(af[i], bfr[j], acc[i][j]);
    }
    __syncthreads();
  }

  int proj = tn >> 4;
  int h = tn & 15;
  const float* bias = (proj == 0) ? b0 : (proj == 1) ? b1 : b2;
  if (proj < 2) {
    u16* out = (proj == 0) ? outQ : outK;
    float scale = (proj == 0) ? 0.08838834764831845f : 1.0f;
#pragma unroll
    for (int i = 0; i < 4; ++i) {
      int s0 = tm * 128 + wm * 64 + i * 16 + q * 4;
#pragma unroll
      for (int j = 0; j < 4; ++j) {
        int d = wn * 64 + j * 16 + c;
        float bv = bias[h * 128 + d];
        uint32_t p01 = pk2((acc[i][j][0] + bv) * scale, (acc[i][j][1] + bv) * scale);
        uint32_t p23 = pk2((acc[i][j][2] + bv) * scale, (acc[i][j][3] + bv) * scale);
        u16* o = out + ((size_t)h * 2048 + s0) * 128 + d;
        o[0]   = (u16)p01;
        o[128] = (u16)(p01 >> 16);
        o[256] = (u16)p23;
        o[384] = (u16)(p23 >> 16);
      }
    }
  } else {
    // V: transpose via LDS -> Vt[h][d][s]
    u16* Cs = (u16*)smem;  // [128][136]
#pragma unroll
    for (int i = 0; i < 4; ++i) {
      int sl = wm * 64 + i * 16 + q * 4;
#pragma unroll
      for (int j = 0; j < 4; ++j) {
        int dl = wn * 64 + j * 16 + c;
        float bv = bias[h * 128 + dl];
        uint2 pk;
        pk.x = pk2(acc[i][j][0] + bv, acc[i][j][1] + bv);
        pk.y = pk2(acc[i][j][2] + bv, acc[i][j][3] + bv);
        *(uint2*)(Cs + dl * 136 + sl) = pk;
      }
    }
    __syncthreads();
#pragma unroll
    for (int rr = 0; rr < 8; ++rr) {
      int d = rr * 16 + (tid >> 4);
      int sc = (tid & 15) * 8;
      uint4 vv = *(const uint4*)(Cs + d * 136 + sc);
      *(uint4*)(outVT + ((size_t)(h * 128 + d)) * 2048 + tm * 128 + sc) = vv;
    }
  }
}

// ---------------- O-projection GEMM: 128x64 tiles, XCD B-resident swizzle ----------------
// 1D grid 512: XCD x owns tn in [4x,4x+4) (1 MB B panels L2-resident), all 16 tm.
__launch_bounds__(256, 2)
__global__ void gemm_op(const u16* __restrict__ A, const u16* __restrict__ Bt,
                        const float* __restrict__ bias, float* __restrict__ out) {
  extern __shared__ char smem[];
  u16* As = (u16*)smem;              // [128][64]  16 KB
  u16* Bs = (u16*)(smem + 16384);    // [64][64]    8 KB
  const int K = 2048;
  const int tid = threadIdx.x;
  const int lane = tid & 63, wid = tid >> 6;
  const int c = lane & 15, q = lane >> 4;
  const int wm = wid >> 1, wn = wid & 1;
  const int bid = blockIdx.x;
  const int xcd = bid & 7, idx = bid >> 3;     // idx 0..63
  const int tn = xcd * 4 + (idx & 3);
  const int tm = idx >> 2;
  const size_t Abase = (size_t)tm * 128 * K;
  const size_t Bbase = (size_t)tn * 64 * K;

  f32x4 acc[4][2] = {};

  for (int kt = 0; kt < K / 64; ++kt) {
#pragma unroll
    for (int t = 0; t < 4; ++t) {
      int slot = wid * 256 + t * 64 + lane;
      int row = slot >> 3, cs = slot & 7;
      int cc = cs ^ (row & 7);
      gl_lds16(A + Abase + (size_t)row * K + kt * 64 + cc * 8,
               (char*)As + (size_t)(wid * 256 + t * 64) * 16);
    }
#pragma unroll
    for (int t = 0; t < 2; ++t) {
      int slot = wid * 128 + t * 64 + lane;
      int row = slot >> 3, cs = slot & 7;
      int cc = cs ^ (row & 7);
      gl_lds16(Bt + Bbase + (size_t)row * K + kt * 64 + cc * 8,
               (char*)Bs + (size_t)(wid * 128 + t * 64) * 16);
    }
    __syncthreads();
#pragma unroll
    for (int kc = 0; kc < 2; ++kc) {
      bf16x8 af[4], bfr[2];
#pragma unroll
      for (int i = 0; i < 4; ++i) {
        int rowa = wm * 64 + i * 16 + c;
        int cha = ((kc << 2) | q) ^ (rowa & 7);
        af[i] = *(const bf16x8*)((const char*)As + rowa * 128 + cha * 16);
      }
#pragma unroll
      for (int j = 0; j < 2; ++j) {
        int rowb = wn * 32 + j * 16 + c;
        int chb = ((kc << 2) | q) ^ (rowb & 7);
        bfr[j] = *(const bf16x8*)((const char*)Bs + rowb * 128 + chb * 16);
      }
#pragma unroll
      for (int i = 0; i < 4; ++i)
#pragma unroll
        for (int j = 0; j < 2; ++j)
          acc[i][j] = mfma16(af[i], bfr[j], acc[i][j]);
    }
    __syncthreads();
  }

#pragma unroll
  for (int i = 0; i < 4; ++i) {
    int rowg = tm * 128 + wm * 64 + i * 16 + q * 4;
#pragma unroll
    for (int j = 0; j < 2; ++j) {
      int colg = tn * 64 + wn * 32 + j * 16 + c;
      float bv = bias[colg];
#pragma unroll
      for (int r = 0; r < 4; ++r)
        out[(size_t)(rowg + r) * 2048 + colg] = acc[i][j][r] + bv;
    }
  }
}

// ---------------- flash attention, causal, split-K(2), max-free softmax ----------------
// Double-buffered K/V staging with counted vmcnt(8); P slab reuses the dead current
// K buffer after the QK^T barrier. Raw s_barrier (no vmcnt drain). 2 blocks/CU.
// Stores RAW partial O (bf16) + row-sum l (fp32 in d_out scratch); combine divides
// by (l0+l1). qt=0/split1 has l=0,O=0 rows — benign raw; NEVER normalize per-split.
__launch_bounds__(256, 2)
__global__ void attn_kernel(const u16* __restrict__ Qb, const u16* __restrict__ Kb,
                            const u16* __restrict__ Vt,
                            u16* __restrict__ Opb, float* __restrict__ lpb) {
  extern __shared__ char smem[];
  int b = blockIdx.x;
  int split, qt, h;
  if (b < 256) { split = 0; qt = b >> 4; h = b & 15; }
  else { split = 1; int idx = b - 256; qt = 15 - (idx >> 4); h = idx & 15; }
  u16* Op = Opb + (size_t)split * 4194304;
  float* lp = lpb + (size_t)split * 32768;
  const int ktBase = split ? (qt + 1) : 0;
  const int ntiles = qt + 1;

  const int tid = threadIdx.x, lane = tid & 63, wid = tid >> 6;
  const int c = lane & 15, q = lane >> 4;

  bf16x8 qf[2][4];
#pragma unroll
  for (int i = 0; i < 2; ++i) {
    int s = qt * 128 + wid * 32 + i * 16 + c;
    const u16* qrow = Qb + ((size_t)h * 2048 + s) * 128;
#pragma unroll
    for (int kc = 0; kc < 4; ++kc)
      qf[i][kc] = *(const bf16x8*)(qrow + kc * 32 + q * 8);
  }

  f32x4 oacc[2][8] = {};
  float lst[2][4] = {};

  auto STAGE = [&](int kt, int buf) {
    char* Kd = smem + buf * 32768;
    char* Vd = smem + buf * 32768 + 16384;
#pragma unroll
    for (int t = 0; t < 4; ++t) {
      int slot = (wid * 4 + t) * 64 + lane;
      int rowk = slot >> 4, csk = slot & 15;
      int cck = csk ^ (rowk & 7);
      const u16* gk = Kb + ((size_t)h * 2048 + kt * 64 + rowk) * 128 + cck * 8;
      gl_lds16(gk, Kd + (size_t)((wid * 4 + t) * 64) * 16);
      int rowv = slot >> 3, csv = slot & 7;
      int ccv = csv ^ (rowv & 7);
      const u16* gv = Vt + ((size_t)(h * 128 + rowv)) * 2048 + kt * 64 + ccv * 8;
      gl_lds16(gv, Vd + (size_t)((wid * 4 + t) * 64) * 16);
    }
  };

  STAGE(ktBase, 0);
  int cur = 0;

  for (int tt = 0; tt < ntiles; ++tt) {
    const int kt = ktBase + tt;
    if (tt + 1 < ntiles) {
      STAGE(kt + 1, cur ^ 1);
      __builtin_amdgcn_sched_barrier(0);
      asm volatile("s_waitcnt vmcnt(8)" ::: "memory");
    } else {
      asm volatile("s_waitcnt vmcnt(0)" ::: "memory");
    }
    __builtin_amdgcn_sched_barrier(0);
    bar();

    const char* Ksb = smem + cur * 32768;
    const char* Vsb = smem + cur * 32768 + 16384;

    f32x4 sacc[2][4] = {};
    __builtin_amdgcn_s_setprio(1);
#pragma unroll
    for (int kc = 0; kc < 4; ++kc) {
      bf16x8 bfr[4];
#pragma unroll
      for (int j = 0; j < 4; ++j) {
        int row = j * 16 + c;
        int ch = ((kc << 2) | q) ^ (row & 7);
        bfr[j] = *(const bf16x8*)(Ksb + row * 256 + ch * 16);
      }
#pragma unroll
      for (int i = 0; i < 2; ++i)
#pragma unroll
        for (int j = 0; j < 4; ++j)
          sacc[i][j] = mfma16(qf[i][kc], bfr[j], sacc[i][j]);
    }
    __builtin_amdgcn_s_setprio(0);
    bar();

    if (kt >= 2 * qt) {
#pragma unroll
      for (int i = 0; i < 2; ++i)
#pragma unroll
        for (int j = 0; j < 4; ++j) {
          int key = kt * 64 + j * 16 + c;
#pragma unroll
          for (int r = 0; r < 4; ++r) {
            int qrow = qt * 128 + wid * 32 + i * 16 + q * 4 + r;
            if (key > qrow) sacc[i][j][r] = -1e30f;
          }
        }
    }

#pragma unroll
    for (int i = 0; i < 2; ++i)
#pragma unroll
      for (int j = 0; j < 4; ++j)
#pragma unroll
        for (int r = 0; r < 4; ++r) {
          float p = __builtin_amdgcn_exp2f(sacc[i][j][r] * LOG2E);
          sacc[i][j][r] = p;
          lst[i][r] += p;
        }

    char* Pw = smem + cur * 32768 + wid * 4096;
#pragma unroll
    for (int i = 0; i < 2; ++i)
#pragma unroll
      for (int j = 0; j < 4; ++j) {
        uint32_t p01 = pk2(sacc[i][j][0], sacc[i][j][1]);
        uint32_t p23 = pk2(sacc[i][j][2], sacc[i][j][3]);
        int cb = (j << 1) | (c >> 3);
        int r0 = i * 16 + q * 4;
        int wb = (c & 7) << 1;
        *(u16*)(Pw + (r0 + 0) * 128 + ((cb ^ ((r0 + 0) & 7)) << 4) + wb) = (u16)p01;
        *(u16*)(Pw + (r0 + 1) * 128 + ((cb ^ ((r0 + 1) & 7)) << 4) + wb) = (u16)(p01 >> 16);
        *(u16*)(Pw + (r0 + 2) * 128 + ((cb ^ ((r0 + 2) & 7)) << 4) + wb) = (u16)p23;
        *(u16*)(Pw + (r0 + 3) * 128 + ((cb ^ ((r0 + 3) & 7)) << 4) + wb) = (u16)(p23 >> 16);
      }

    __builtin_amdgcn_s_setprio(1);
#pragma unroll
    for (int kc = 0; kc < 2; ++kc) {
      bf16x8 af[2], bv[8];
#pragma unroll
      for (int i = 0; i < 2; ++i) {
        int prow = i * 16 + c;
        af[i] = *(const bf16x8*)(Pw + prow * 128 + ((((kc << 2) | q) ^ (prow & 7)) << 4));
      }
#pragma unroll
      for (int jo = 0; jo < 8; ++jo) {
        int row = jo * 16 + c;
        int ch = ((kc << 2) | q) ^ (row & 7);
        bv[jo] = *(const bf16x8*)(Vsb + row * 128 + ch * 16);
      }
#pragma unroll
      for (int i = 0; i < 2; ++i)
#pragma unroll
        for (int jo = 0; jo < 8; ++jo)
          oacc[i][jo] = mfma16(bv[jo], af[i], oacc[i][jo]);
    }
    __builtin_amdgcn_s_setprio(0);
    bar();
    cur ^= 1;
  }

#pragma unroll
  for (int i = 0; i < 2; ++i)
#pragma unroll
    for (int r = 0; r < 4; ++r) {
      float l = lst[i][r];
      l += __shfl_xor(l, 1);
      l += __shfl_xor(l, 2);
      l += __shfl_xor(l, 4);
      l += __shfl_xor(l, 8);
      if (c == 0)
        lp[(size_t)h * 2048 + qt * 128 + wid * 32 + i * 16 + q * 4 + r] = l;
    }
#pragma unroll
  for (int i = 0; i < 2; ++i) {
    int s = qt * 128 + wid * 32 + i * 16 + c;
#pragma unroll
    for (int jo = 0; jo < 8; ++jo) {
      uint2 o;
      o.x = pk2(oacc[i][jo][0], oacc[i][jo][1]);
      o.y = pk2(oacc[i][jo][2], oacc[i][jo][3]);
      *(uint2*)(Op + ((size_t)h * 2048 + s) * 128 + jo * 16 + q * 4) = o;
    }
  }
}

// ---------------- combine: AO = (O0+O1)/(l0+l1), bf16 out [s][h*128+d] ----------------
__global__ void attn_combine(const u16* __restrict__ Opb, const float* __restrict__ lpb,
                             u16* __restrict__ AO) {
  int g = blockIdx.x * 256 + threadIdx.x;
  int row = g >> 4;
  int dd = (g & 15) * 8;
  int h = row >> 11, s = row & 2047;
  float inv = 1.0f / (lpb[row] + lpb[row + 32768]);
  uint4 a = *(const uint4*)(Opb + (size_t)row * 128 + dd);
  uint4 bb = *(const uint4*)(Opb + 4194304 + (size_t)row * 128 + dd);
  const u16* pa = (const u16*)&a;
  const u16* pb = (const u16*)&bb;
  uint4 res;
  uint32_t* pr = (uint32_t*)&res;
#pragma unroll
  for (int t = 0; t < 4; ++t)
    pr[t] = pk2((bf2f(pa[2 * t]) + bf2f(pb[2 * t])) * inv,
                (bf2f(pa[2 * t + 1]) + bf2f(pb[2 * t + 1])) * inv);
  *(uint4*)(AO + (size_t)s * 2048 + h * 128 + dd) = res;
}

extern "C" void kernel_launch(void* const* d_in, const int* in_sizes, int n_in,
                              void* d_out, int out_size, void* d_ws, size_t ws_size,
                              hipStream_t stream) {
  const float* x  = (const float*)d_in[0];
  const float* Wq = (const float*)d_in[1];
  const float* bq = (const float*)d_in[2];
  const float* Wk = (const float*)d_in[3];
  const float* bk = (const float*)d_in[4];
  const float* Wv = (const float*)d_in[5];
  const float* bv = (const float*)d_in[6];
  const float* Wo = (const float*)d_in[7];
  const float* bo = (const float*)d_in[8];

  char* ws = (char*)d_ws;
  u16* xb = (u16*)(ws);                          // x bf16            0- 8 MB
  u16* wt = (u16*)(ws + (size_t)8  * 1048576);   // Wq/k/v/o^T bf16   8-40 MB
  u16* Qb = (u16*)(ws + (size_t)40 * 1048576);   // Q [h][s][d]      40-48 MB
  u16* Kb = (u16*)(ws + (size_t)48 * 1048576);   // K [h][s][d]      48-56 MB
  u16* Vt = (u16*)(ws + (size_t)56 * 1048576);   // V^T [h][d][s]    56-64 MB
  u16* AO = (u16*)(ws + (size_t)64 * 1048576);   // attn out [s][D]  64-72 MB
  u16* Opb = (u16*)(ws);
  float* lpb = (float*)d_out;

  prep_kernel<<<dim3(32, 32, 5), 256, 0, stream>>>(Wq, Wk, Wv, Wo, wt, x, xb);
  gemm_bt<<<768, 256, 34816, stream>>>(xb, wt, bq, bk, bv, Qb, Kb, Vt);
  attn_kernel<<<512, 256, 65536, stream>>>(Qb, Kb, Vt, Opb, lpb);
  attn_combine<<<2048, 256, 0, stream>>>(Opb, lpb, AO);
  gemm_op<<<512, 256, 24576, stream>>>(AO, wt + (size_t)3 * 2048 * 2048,
                                       bo, (float*)d_out);
}

// Round 5
// 246.148 us; speedup vs baseline: 1.2338x; 1.0360x over previous
//
#include <hip/hip_runtime.h>
#include <hip/hip_bf16.h>
#include <stdint.h>

typedef unsigned short u16;
typedef __attribute__((ext_vector_type(8))) __bf16 bf16x8;
typedef __attribute__((ext_vector_type(4))) float f32x4;

#define LOG2E 1.4426950408889634f

__device__ __forceinline__ float bf2f(u16 u) {
  union { uint32_t u; float f; } v; v.u = ((uint32_t)u) << 16;
  return v.f;
}

// packed cvt: two fp32 -> one u32 holding (lo=a, hi=b) bf16
__device__ __forceinline__ uint32_t pk2(float a, float b) {
  union { __hip_bfloat162 h; uint32_t u; } x;
  x.h = __float22bfloat162_rn(make_float2(a, b));
  return x.u;
}

__device__ __forceinline__ void gl_lds16(const void* g, void* l) {
  __builtin_amdgcn_global_load_lds((const __attribute__((address_space(1))) void*)g,
                                   (__attribute__((address_space(3))) void*)l,
                                   16, 0, 0);
}

__device__ __forceinline__ f32x4 mfma16(bf16x8 a, bf16x8 b, f32x4 c) {
  return __builtin_amdgcn_mfma_f32_16x16x32_bf16(a, b, c, 0, 0, 0);
}

// raw workgroup barrier with compiler memory fence (no vmcnt/lgkm drain)
__device__ __forceinline__ void bar() {
  asm volatile("" ::: "memory");
  __builtin_amdgcn_s_barrier();
  asm volatile("" ::: "memory");
}

// ---------------- fused preprocessing ----------------
// z<4: transpose+cvt W_z[k][n] fp32 -> Wt[n][k] bf16 (grid (32,32) per z)
// z==4: x fp32 -> bf16 elementwise (1024 logical blocks via (y*32+x), 16 floats/thread)
__global__ void prep_kernel(const float* __restrict__ W0, const float* __restrict__ W1,
                            const float* __restrict__ W2, const float* __restrict__ W3,
                            u16* __restrict__ wout,
                            const float* __restrict__ xsrc, u16* __restrict__ xdst) {
  int z = blockIdx.z;
  if (z == 4) {
    int lin = blockIdx.y * 32 + blockIdx.x;   // 0..1023
    int tid = threadIdx.x;
#pragma unroll
    for (int p = 0; p < 4; ++p) {
      int i4 = (lin * 4 + p) * 256 + tid;     // float4 index, coalesced per pass
      float4 f = *(const float4*)(xsrc + (size_t)i4 * 4);
      uint2 o;
      o.x = pk2(f.x, f.y);
      o.y = pk2(f.z, f.w);
      *(uint2*)(xdst + (size_t)i4 * 4) = o;
    }
    return;
  }
  __shared__ float tile[64][65];
  const float* W = (z == 0) ? W0 : (z == 1) ? W1 : (z == 2) ? W2 : W3;
  u16* dst = wout + (size_t)z * 2048 * 2048;
  int k0 = blockIdx.y * 64, n0 = blockIdx.x * 64;
  int lx = threadIdx.x & 63, ly = threadIdx.x >> 6;
#pragma unroll
  for (int p = 0; p < 16; ++p) {
    int row = p * 4 + ly;
    tile[row][lx] = W[(size_t)(k0 + row) * 2048 + n0 + lx];
  }
  __syncthreads();
  int kc = threadIdx.x & 7;        // 8-wide k chunk
  int rbase = threadIdx.x >> 3;    // 0..31
#pragma unroll
  for (int p = 0; p < 2; ++p) {
    int n = rbase + p * 32;        // n-local row
    uint4 o;
    o.x = pk2(tile[kc * 8 + 0][n], tile[kc * 8 + 1][n]);
    o.y = pk2(tile[kc * 8 + 2][n], tile[kc * 8 + 3][n]);
    o.z = pk2(tile[kc * 8 + 4][n], tile[kc * 8 + 5][n]);
    o.w = pk2(tile[kc * 8 + 6][n], tile[kc * 8 + 7][n]);
    *(uint4*)(dst + (size_t)(n0 + n) * 2048 + k0 + kc * 8) = o;
  }
}

// ---------------- bf16 GEMM, m97-style (PROVEN 55.3 us): QKV projections ----------------
// 1D grid 768, XCD-aware B-resident swizzle: XCD x owns tn in [6x,6x+6) (6 B-panels =
// 3 MB, L2-resident) and streams all A (8 MB, L3-served). 768 % 8 == 0 -> bijective.
// tn in [0,48): proj=tn>>4, h=tn&15
//   proj 0: Q[h][s][d] = (acc+bq)/sqrt(128); proj 1: K[h][s][d]; proj 2: Vt[h][d][s]
__launch_bounds__(256, 2)
__global__ void gemm_bt(const u16* __restrict__ A, const u16* __restrict__ Bt,
                        const float* __restrict__ b0, const float* __restrict__ b1,
                        const float* __restrict__ b2,
                        u16* __restrict__ outQ, u16* __restrict__ outK,
                        u16* __restrict__ outVT) {
  extern __shared__ char smem[];
  u16* As = (u16*)smem;              // [128][64] bf16, 16B-chunk XOR swizzled
  u16* Bs = (u16*)(smem + 16384);
  const int K = 2048;
  const int tid = threadIdx.x;
  const int lane = tid & 63, wid = tid >> 6;
  const int c = lane & 15, q = lane >> 4;
  const int wm = wid >> 1, wn = wid & 1;
  // XCD swizzle: bid%8 = XCD (round-robin dispatch); give each XCD 6 tn cols x 16 tm
  const int bid = blockIdx.x;
  const int xcd = bid & 7, idx = bid >> 3;     // idx 0..95
  const int tn = xcd * 6 + idx % 6;
  const int tm = idx / 6;
  const size_t Abase = (size_t)tm * 128 * K;
  const size_t Bbase = (size_t)tn * 128 * K;

  f32x4 acc[4][4] = {};

  for (int kt = 0; kt < K / 64; ++kt) {
#pragma unroll
    for (int t = 0; t < 4; ++t) {
      int slot = wid * 256 + t * 64 + lane;
      int row = slot >> 3, cs = slot & 7;
      int cc = cs ^ (row & 7);
      const u16* ga = A + Abase + (size_t)row * K + kt * 64 + cc * 8;
      gl_lds16(ga, (char*)As + (size_t)(wid * 256 + t * 64) * 16);
      const u16* gb = Bt + Bbase + (size_t)row * K + kt * 64 + cc * 8;
      gl_lds16(gb, (char*)Bs + (size_t)(wid * 256 + t * 64) * 16);
    }
    __syncthreads();
#pragma unroll
    for (int kc = 0; kc < 2; ++kc) {
      bf16x8 af[4], bfr[4];
#pragma unroll
      for (int i = 0; i < 4; ++i) {
        int rowa = wm * 64 + i * 16 + c;
        int cha = ((kc << 2) | q) ^ (rowa & 7);
        af[i] = *(const bf16x8*)((const char*)As + rowa * 128 + cha * 16);
        int rowb = wn * 64 + i * 16 + c;
        int chb = ((kc << 2) | q) ^ (rowb & 7);
        bfr[i] = *(const bf16x8*)((const char*)Bs + rowb * 128 + chb * 16);
      }
#pragma unroll
      for (int i = 0; i < 4; ++i)
#pragma unroll
        for (int j = 0; j < 4; ++j)
          acc[i][j] = mfma16(af[i], bfr[j], acc[i][j]);
    }
    __syncthreads();
  }

  int proj = tn >> 4;
  int h = tn & 15;
  const float* bias = (proj == 0) ? b0 : (proj == 1) ? b1 : b2;
  if (proj < 2) {
    u16* out = (proj == 0) ? outQ : outK;
    float scale = (proj == 0) ? 0.08838834764831845f : 1.0f;
#pragma unroll
    for (int i = 0; i < 4; ++i) {
      int s0 = tm * 128 + wm * 64 + i * 16 + q * 4;
#pragma unroll
      for (int j = 0; j < 4; ++j) {
        int d = wn * 64 + j * 16 + c;
        float bv = bias[h * 128 + d];
        uint32_t p01 = pk2((acc[i][j][0] + bv) * scale, (acc[i][j][1] + bv) * scale);
        uint32_t p23 = pk2((acc[i][j][2] + bv) * scale, (acc[i][j][3] + bv) * scale);
        u16* o = out + ((size_t)h * 2048 + s0) * 128 + d;
        o[0]   = (u16)p01;
        o[128] = (u16)(p01 >> 16);
        o[256] = (u16)p23;
        o[384] = (u16)(p23 >> 16);
      }
    }
  } else {
    // V: transpose via LDS -> Vt[h][d][s]
    u16* Cs = (u16*)smem;  // [128][136]
#pragma unroll
    for (int i = 0; i < 4; ++i) {
      int sl = wm * 64 + i * 16 + q * 4;
#pragma unroll
      for (int j = 0; j < 4; ++j) {
        int dl = wn * 64 + j * 16 + c;
        float bv = bias[h * 128 + dl];
        uint2 pk;
        pk.x = pk2(acc[i][j][0] + bv, acc[i][j][1] + bv);
        pk.y = pk2(acc[i][j][2] + bv, acc[i][j][3] + bv);
        *(uint2*)(Cs + dl * 136 + sl) = pk;
      }
    }
    __syncthreads();
#pragma unroll
    for (int rr = 0; rr < 8; ++rr) {
      int d = rr * 16 + (tid >> 4);
      int sc = (tid & 15) * 8;
      uint4 vv = *(const uint4*)(Cs + d * 136 + sc);
      *(uint4*)(outVT + ((size_t)(h * 128 + d)) * 2048 + tm * 128 + sc) = vv;
    }
  }
}

// ---------------- O-projection GEMM: 128x128 tiles, triple-buffered counted-vmcnt ----
// REBUILT this round. Grid 256 = 1 block/CU exactly (100% fill). Prior failure mode at
// 256 blocks was the DRAINING K-loop at 1 block/CU (no co-resident block to hide
// latency); fix is intra-block pipelining: 3 LDS buffers (96 KB), stage 2 tiles ahead,
// counted vmcnt(16)/(8)/(0) so the current tile always landed ~2 K-steps ago.
// Buffer reuse ledger: iter kt stages tile kt+2 into buf (kt+2)%3 == (kt-1)%3, whose
// reads completed before iter kt-1's end-barrier -> race-free.
// LDS layout/compute verbatim from gemm_bt (proven conflict-free). XCD: 2 B-panels
// (1 MB) per XCD L2-resident; 256 % 8 == 0 bijective.
__launch_bounds__(256, 1)
__global__ void gemm_op(const u16* __restrict__ A, const u16* __restrict__ Bt,
                        const float* __restrict__ bias, float* __restrict__ out) {
  extern __shared__ char smem[];
  const int K = 2048, NT = 32;
  const int tid = threadIdx.x;
  const int lane = tid & 63, wid = tid >> 6;
  const int c = lane & 15, q = lane >> 4;
  const int wm = wid >> 1, wn = wid & 1;
  const int bid = blockIdx.x;
  const int xcd = bid & 7, idx = bid >> 3;     // idx 0..31
  const int tn = xcd * 2 + (idx & 1);
  const int tm = idx >> 1;
  const size_t Abase = (size_t)tm * 128 * K;
  const size_t Bbase = (size_t)tn * 128 * K;

  f32x4 acc[4][4] = {};

  auto STAGE = [&](int kt, int buf) {
    char* As = smem + buf * 32768;
    char* Bs = smem + buf * 32768 + 16384;
#pragma unroll
    for (int t = 0; t < 4; ++t) {
      int slot = wid * 256 + t * 64 + lane;
      int row = slot >> 3, cs = slot & 7;
      int cc = cs ^ (row & 7);
      gl_lds16(A + Abase + (size_t)row * K + kt * 64 + cc * 8, As + (size_t)slot * 16);
      gl_lds16(Bt + Bbase + (size_t)row * K + kt * 64 + cc * 8, Bs + (size_t)slot * 16);
    }
  };

  STAGE(0, 0);
  STAGE(1, 1);

  for (int kt = 0; kt < NT; ++kt) {
    const int buf = kt % 3;
    if (kt + 2 < NT) {
      STAGE(kt + 2, (kt + 2) % 3);
      asm volatile("s_waitcnt vmcnt(16)" ::: "memory");
    } else if (kt + 1 < NT) {
      asm volatile("s_waitcnt vmcnt(8)" ::: "memory");
    } else {
      asm volatile("s_waitcnt vmcnt(0)" ::: "memory");
    }
    __builtin_amdgcn_sched_barrier(0);
    bar();

    const char* As = smem + buf * 32768;
    const char* Bs = smem + buf * 32768 + 16384;
#pragma unroll
    for (int kc = 0; kc < 2; ++kc) {
      bf16x8 af[4], bfr[4];
#pragma unroll
      for (int i = 0; i < 4; ++i) {
        int rowa = wm * 64 + i * 16 + c;
        int cha = ((kc << 2) | q) ^ (rowa & 7);
        af[i] = *(const bf16x8*)(As + rowa * 128 + cha * 16);
        int rowb = wn * 64 + i * 16 + c;
        int chb = ((kc << 2) | q) ^ (rowb & 7);
        bfr[i] = *(const bf16x8*)(Bs + rowb * 128 + chb * 16);
      }
      __builtin_amdgcn_s_setprio(1);
#pragma unroll
      for (int i = 0; i < 4; ++i)
#pragma unroll
        for (int j = 0; j < 4; ++j)
          acc[i][j] = mfma16(af[i], bfr[j], acc[i][j]);
      __builtin_amdgcn_s_setprio(0);
    }
    bar();
  }

#pragma unroll
  for (int i = 0; i < 4; ++i) {
    int rowg = tm * 128 + wm * 64 + i * 16 + q * 4;
#pragma unroll
    for (int j = 0; j < 4; ++j) {
      int colg = tn * 128 + wn * 64 + j * 16 + c;
      float bv = bias[colg];
#pragma unroll
      for (int r = 0; r < 4; ++r)
        out[(size_t)(rowg + r) * 2048 + colg] = acc[i][j][r] + bv;
    }
  }
}

// ---------------- flash attention, causal, split-K(2), max-free softmax ----------------
// Double-buffered K/V staging with counted vmcnt(8); P slab reuses the dead current
// K buffer after the QK^T barrier. Raw s_barrier (no vmcnt drain). 2 blocks/CU.
// Stores RAW partial O (bf16) + row-sum l (fp32 in d_out scratch); combine divides
// by (l0+l1). qt=0/split1 has l=0,O=0 rows — benign raw; NEVER normalize per-split.
__launch_bounds__(256, 2)
__global__ void attn_kernel(const u16* __restrict__ Qb, const u16* __restrict__ Kb,
                            const u16* __restrict__ Vt,
                            u16* __restrict__ Opb, float* __restrict__ lpb) {
  extern __shared__ char smem[];
  int b = blockIdx.x;
  int split, qt, h;
  if (b < 256) { split = 0; qt = b >> 4; h = b & 15; }
  else { split = 1; int idx = b - 256; qt = 15 - (idx >> 4); h = idx & 15; }
  u16* Op = Opb + (size_t)split * 4194304;
  float* lp = lpb + (size_t)split * 32768;
  const int ktBase = split ? (qt + 1) : 0;
  const int ntiles = qt + 1;

  const int tid = threadIdx.x, lane = tid & 63, wid = tid >> 6;
  const int c = lane & 15, q = lane >> 4;

  bf16x8 qf[2][4];
#pragma unroll
  for (int i = 0; i < 2; ++i) {
    int s = qt * 128 + wid * 32 + i * 16 + c;
    const u16* qrow = Qb + ((size_t)h * 2048 + s) * 128;
#pragma unroll
    for (int kc = 0; kc < 4; ++kc)
      qf[i][kc] = *(const bf16x8*)(qrow + kc * 32 + q * 8);
  }

  f32x4 oacc[2][8] = {};
  float lst[2][4] = {};

  auto STAGE = [&](int kt, int buf) {
    char* Kd = smem + buf * 32768;
    char* Vd = smem + buf * 32768 + 16384;
#pragma unroll
    for (int t = 0; t < 4; ++t) {
      int slot = (wid * 4 + t) * 64 + lane;
      int rowk = slot >> 4, csk = slot & 15;
      int cck = csk ^ (rowk & 7);
      const u16* gk = Kb + ((size_t)h * 2048 + kt * 64 + rowk) * 128 + cck * 8;
      gl_lds16(gk, Kd + (size_t)((wid * 4 + t) * 64) * 16);
      int rowv = slot >> 3, csv = slot & 7;
      int ccv = csv ^ (rowv & 7);
      const u16* gv = Vt + ((size_t)(h * 128 + rowv)) * 2048 + kt * 64 + ccv * 8;
      gl_lds16(gv, Vd + (size_t)((wid * 4 + t) * 64) * 16);
    }
  };

  STAGE(ktBase, 0);
  int cur = 0;

  for (int tt = 0; tt < ntiles; ++tt) {
    const int kt = ktBase + tt;
    if (tt + 1 < ntiles) {
      STAGE(kt + 1, cur ^ 1);
      __builtin_amdgcn_sched_barrier(0);
      asm volatile("s_waitcnt vmcnt(8)" ::: "memory");
    } else {
      asm volatile("s_waitcnt vmcnt(0)" ::: "memory");
    }
    __builtin_amdgcn_sched_barrier(0);
    bar();

    const char* Ksb = smem + cur * 32768;
    const char* Vsb = smem + cur * 32768 + 16384;

    f32x4 sacc[2][4] = {};
    __builtin_amdgcn_s_setprio(1);
#pragma unroll
    for (int kc = 0; kc < 4; ++kc) {
      bf16x8 bfr[4];
#pragma unroll
      for (int j = 0; j < 4; ++j) {
        int row = j * 16 + c;
        int ch = ((kc << 2) | q) ^ (row & 7);
        bfr[j] = *(const bf16x8*)(Ksb + row * 256 + ch * 16);
      }
#pragma unroll
      for (int i = 0; i < 2; ++i)
#pragma unroll
        for (int j = 0; j < 4; ++j)
          sacc[i][j] = mfma16(qf[i][kc], bfr[j], sacc[i][j]);
    }
    __builtin_amdgcn_s_setprio(0);
    bar();

    if (kt >= 2 * qt) {
#pragma unroll
      for (int i = 0; i < 2; ++i)
#pragma unroll
        for (int j = 0; j < 4; ++j) {
          int key = kt * 64 + j * 16 + c;
#pragma unroll
          for (int r = 0; r < 4; ++r) {
            int qrow = qt * 128 + wid * 32 + i * 16 + q * 4 + r;
            if (key > qrow) sacc[i][j][r] = -1e30f;
          }
        }
    }

#pragma unroll
    for (int i = 0; i < 2; ++i)
#pragma unroll
      for (int j = 0; j < 4; ++j)
#pragma unroll
        for (int r = 0; r < 4; ++r) {
          float p = __builtin_amdgcn_exp2f(sacc[i][j][r] * LOG2E);
          sacc[i][j][r] = p;
          lst[i][r] += p;
        }

    char* Pw = smem + cur * 32768 + wid * 4096;
#pragma unroll
    for (int i = 0; i < 2; ++i)
#pragma unroll
      for (int j = 0; j < 4; ++j) {
        uint32_t p01 = pk2(sacc[i][j][0], sacc[i][j][1]);
        uint32_t p23 = pk2(sacc[i][j][2], sacc[i][j][3]);
        int cb = (j << 1) | (c >> 3);
        int r0 = i * 16 + q * 4;
        int wb = (c & 7) << 1;
        *(u16*)(Pw + (r0 + 0) * 128 + ((cb ^ ((r0 + 0) & 7)) << 4) + wb) = (u16)p01;
        *(u16*)(Pw + (r0 + 1) * 128 + ((cb ^ ((r0 + 1) & 7)) << 4) + wb) = (u16)(p01 >> 16);
        *(u16*)(Pw + (r0 + 2) * 128 + ((cb ^ ((r0 + 2) & 7)) << 4) + wb) = (u16)p23;
        *(u16*)(Pw + (r0 + 3) * 128 + ((cb ^ ((r0 + 3) & 7)) << 4) + wb) = (u16)(p23 >> 16);
      }

    __builtin_amdgcn_s_setprio(1);
#pragma unroll
    for (int kc = 0; kc < 2; ++kc) {
      bf16x8 af[2], bv[8];
#pragma unroll
      for (int i = 0; i < 2; ++i) {
        int prow = i * 16 + c;
        af[i] = *(const bf16x8*)(Pw + prow * 128 + ((((kc << 2) | q) ^ (prow & 7)) << 4));
      }
#pragma unroll
      for (int jo = 0; jo < 8; ++jo) {
        int row = jo * 16 + c;
        int ch = ((kc << 2) | q) ^ (row & 7);
        bv[jo] = *(const bf16x8*)(Vsb + row * 128 + ch * 16);
      }
#pragma unroll
      for (int i = 0; i < 2; ++i)
#pragma unroll
        for (int jo = 0; jo < 8; ++jo)
          oacc[i][jo] = mfma16(bv[jo], af[i], oacc[i][jo]);
    }
    __builtin_amdgcn_s_setprio(0);
    bar();
    cur ^= 1;
  }

#pragma unroll
  for (int i = 0; i < 2; ++i)
#pragma unroll
    for (int r = 0; r < 4; ++r) {
      float l = lst[i][r];
      l += __shfl_xor(l, 1);
      l += __shfl_xor(l, 2);
      l += __shfl_xor(l, 4);
      l += __shfl_xor(l, 8);
      if (c == 0)
        lp[(size_t)h * 2048 + qt * 128 + wid * 32 + i * 16 + q * 4 + r] = l;
    }
#pragma unroll
  for (int i = 0; i < 2; ++i) {
    int s = qt * 128 + wid * 32 + i * 16 + c;
#pragma unroll
    for (int jo = 0; jo < 8; ++jo) {
      uint2 o;
      o.x = pk2(oacc[i][jo][0], oacc[i][jo][1]);
      o.y = pk2(oacc[i][jo][2], oacc[i][jo][3]);
      *(uint2*)(Op + ((size_t)h * 2048 + s) * 128 + jo * 16 + q * 4) = o;
    }
  }
}

// ---------------- combine: AO = (O0+O1)/(l0+l1), bf16 out [s][h*128+d] ----------------
__global__ void attn_combine(const u16* __restrict__ Opb, const float* __restrict__ lpb,
                             u16* __restrict__ AO) {
  int g = blockIdx.x * 256 + threadIdx.x;
  int row = g >> 4;
  int dd = (g & 15) * 8;
  int h = row >> 11, s = row & 2047;
  float inv = 1.0f / (lpb[row] + lpb[row + 32768]);
  uint4 a = *(const uint4*)(Opb + (size_t)row * 128 + dd);
  uint4 bb = *(const uint4*)(Opb + 4194304 + (size_t)row * 128 + dd);
  const u16* pa = (const u16*)&a;
  const u16* pb = (const u16*)&bb;
  uint4 res;
  uint32_t* pr = (uint32_t*)&res;
#pragma unroll
  for (int t = 0; t < 4; ++t)
    pr[t] = pk2((bf2f(pa[2 * t]) + bf2f(pb[2 * t])) * inv,
                (bf2f(pa[2 * t + 1]) + bf2f(pb[2 * t + 1])) * inv);
  *(uint4*)(AO + (size_t)s * 2048 + h * 128 + dd) = res;
}

extern "C" void kernel_launch(void* const* d_in, const int* in_sizes, int n_in,
                              void* d_out, int out_size, void* d_ws, size_t ws_size,
                              hipStream_t stream) {
  const float* x  = (const float*)d_in[0];
  const float* Wq = (const float*)d_in[1];
  const float* bq = (const float*)d_in[2];
  const float* Wk = (const float*)d_in[3];
  const float* bk = (const float*)d_in[4];
  const float* Wv = (const float*)d_in[5];
  const float* bv = (const float*)d_in[6];
  const float* Wo = (const float*)d_in[7];
  const float* bo = (const float*)d_in[8];

  char* ws = (char*)d_ws;
  u16* xb = (u16*)(ws);                          // x bf16            0- 8 MB
  u16* wt = (u16*)(ws + (size_t)8  * 1048576);   // Wq/k/v/o^T bf16   8-40 MB
  u16* Qb = (u16*)(ws + (size_t)40 * 1048576);   // Q [h][s][d]      40-48 MB
  u16* Kb = (u16*)(ws + (size_t)48 * 1048576);   // K [h][s][d]      48-56 MB
  u16* Vt = (u16*)(ws + (size_t)56 * 1048576);   // V^T [h][d][s]    56-64 MB
  u16* AO = (u16*)(ws + (size_t)64 * 1048576);   // attn out [s][D]  64-72 MB
  u16* Opb = (u16*)(ws);
  float* lpb = (float*)d_out;

  static bool inited = false;
  if (!inited) {
    hipFuncSetAttribute((const void*)gemm_op,
                        hipFuncAttributeMaxDynamicSharedMemorySize, 98304);
    inited = true;
  }

  prep_kernel<<<dim3(32, 32, 5), 256, 0, stream>>>(Wq, Wk, Wv, Wo, wt, x, xb);
  gemm_bt<<<768, 256, 34816, stream>>>(xb, wt, bq, bk, bv, Qb, Kb, Vt);
  attn_kernel<<<512, 256, 65536, stream>>>(Qb, Kb, Vt, Opb, lpb);
  attn_combine<<<2048, 256, 0, stream>>>(Opb, lpb, AO);
  gemm_op<<<256, 256, 98304, stream>>>(AO, wt + (size_t)3 * 2048 * 2048,
                                       bo, (float*)d_out);
}